// Round 18
// baseline (439.685 us; speedup 1.0000x reference)
//
#include <hip/hip_runtime.h>
#include <hip/hip_fp16.h>

// ---------------------------------------------------------------------------
// 2-layer GCN, CSR with rows sub-sorted by source-half (src<h | src>=h).
// Binding constraint (r16): random-gather hot set must fit per-XCD L2
// (4 MB). Source-split passes: pass A walks A-edges (table rows [0,h) =
// 3.2 MB hot), pass B walks B-edges (rows [h,n)), accumulating onto pass-A
// partials. 2 passes x E/2 edges per layer.
//   build: k_hist -> scans -> k_bin (1024-node buckets)
//          k_bucket2: within-bucket counting sort, key=(dlow<<1)|srchalf
//          -> adj + rp2[2v]=end-of-A, rp2[2v+1]=end-of-row + dinv (8-way ILP)
//   L1: k_mm1 (h1s = dinv*(x@W1), fp16 n x 16) ; gnA -> partial(f32) ;
//       gnB -> z1s = dinv*relu(dinv*(agg+self)+b1) (fp16)
//   L2: gnA(z1s) -> pre ; gnB -> pre (f32, in place)
//   k_out: out = pre @ W2 + b2
// k_gn: THREAD = NODE (r17's (node,half) threads walked adj twice).
// Full 32 B row per edge = 2 independent float4 loads; 2-edge unroll;
// 16 f32 reg accumulators. Region R = bbuf then {h1s,z1s,pre}.
// ---------------------------------------------------------------------------

#define TPB 256
#define BINT 256
#define SEGROWS 64
#define BUCKSH 10
#define BUCKN (1 << BUCKSH)
#define MMN 32

__device__ __forceinline__ int clampi(int v, int n) {
    return v < 0 ? 0 : (v >= n ? n - 1 : v);
}

// --- per-block LDS histogram over contiguous edge range ------------------
__global__ __launch_bounds__(BINT) void k_hist(const int* __restrict__ dst,
                                               int E, int n, int nbuck,
                                               int chunk,
                                               int* __restrict__ hist) {
    __shared__ int lh[256];
    const int b = blockIdx.x;
    const int t = threadIdx.x;
    lh[t] = 0;
    __syncthreads();
    const int start = b * chunk;
    const int end = min(E, start + chunk);
    int i = start + t;
    for (; i + 3 * BINT < end; i += 4 * BINT) {
        int d0 = clampi(dst[i], n);
        int d1 = clampi(dst[i + BINT], n);
        int d2 = clampi(dst[i + 2 * BINT], n);
        int d3 = clampi(dst[i + 3 * BINT], n);
        atomicAdd(&lh[d0 >> BUCKSH], 1);
        atomicAdd(&lh[d1 >> BUCKSH], 1);
        atomicAdd(&lh[d2 >> BUCKSH], 1);
        atomicAdd(&lh[d3 >> BUCKSH], 1);
    }
    for (; i < end; i += BINT) atomicAdd(&lh[clampi(dst[i], n) >> BUCKSH], 1);
    __syncthreads();
    for (int k = t; k < nbuck; k += BINT) hist[b * nbuck + k] = lh[k];
}

// --- segmented column scan stage 1 ---------------------------------------
__global__ void k_scanA1(const int* __restrict__ hist, int nbuck,
                         int* __restrict__ segsum) {
    int k = blockIdx.x * blockDim.x + threadIdx.x;
    int seg = blockIdx.y;
    if (k >= nbuck) return;
    const int* row = hist + (size_t)seg * SEGROWS * nbuck + k;
    int sum = 0;
#pragma unroll
    for (int b = 0; b < SEGROWS; ++b) sum += row[(size_t)b * nbuck];
    segsum[seg * nbuck + k] = sum;
}

// --- stage 2 --------------------------------------------------------------
__global__ void k_scanA2(int* __restrict__ segsum, int nbuck, int nseg,
                         int* __restrict__ colsum) {
    int k = blockIdx.x * blockDim.x + threadIdx.x;
    if (k >= nbuck) return;
    int run = 0;
    for (int sg = 0; sg < nseg; ++sg) {
        int v = segsum[sg * nbuck + k];
        segsum[sg * nbuck + k] = run;
        run += v;
    }
    colsum[k] = run;
}

// --- exclusive scan of colsum -> bstart ----------------------------------
__global__ void k_scanB(const int* __restrict__ colsum, int nbuck, int E,
                        int* __restrict__ bstart) {
    __shared__ int s[256];
    const int t = threadIdx.x;
    int loc[4];
    int a = 0;
#pragma unroll
    for (int i = 0; i < 4; ++i) {
        int idx = 4 * t + i;
        loc[i] = (idx < nbuck) ? colsum[idx] : 0;
        a += loc[i];
    }
    s[t] = a;
    __syncthreads();
#pragma unroll
    for (int off = 1; off < 256; off <<= 1) {
        int v = (t >= off) ? s[t - off] : 0;
        __syncthreads();
        s[t] += v;
        __syncthreads();
    }
    int base = s[t] - a;
#pragma unroll
    for (int i = 0; i < 4; ++i) {
        int idx = 4 * t + i;
        if (idx < nbuck) bstart[idx] = base;
        base += loc[i];
    }
    if (t == 255) bstart[nbuck] = E;
}

// --- stage 3 --------------------------------------------------------------
__global__ void k_scanA3(int* __restrict__ hist, int nbuck,
                         const int* __restrict__ segsum) {
    int k = blockIdx.x * blockDim.x + threadIdx.x;
    int seg = blockIdx.y;
    if (k >= nbuck) return;
    int run = segsum[seg * nbuck + k];
    int* row = hist + (size_t)seg * SEGROWS * nbuck + k;
#pragma unroll
    for (int b = 0; b < SEGROWS; ++b) {
        int v = row[(size_t)b * nbuck];
        row[(size_t)b * nbuck] = run;
        run += v;
    }
}

// --- binning: LDS cursors; 4-way ILP -------------------------------------
__global__ __launch_bounds__(BINT) void k_bin(const int* __restrict__ src,
                                              const int* __restrict__ dst,
                                              int E, int n, int nbuck,
                                              int chunk,
                                              const int* __restrict__ hist,
                                              const int* __restrict__ bstart,
                                              int* __restrict__ bbuf) {
    __shared__ int lcur[256];
    const int b = blockIdx.x;
    const int t = threadIdx.x;
    for (int k = t; k < nbuck; k += BINT)
        lcur[k] = bstart[k] + hist[b * nbuck + k];
    __syncthreads();
    const int start = b * chunk;
    const int end = min(E, start + chunk);
    int i = start + t;
    for (; i + 3 * BINT < end; i += 4 * BINT) {
        int s0 = clampi(src[i], n);
        int s1 = clampi(src[i + BINT], n);
        int s2 = clampi(src[i + 2 * BINT], n);
        int s3 = clampi(src[i + 3 * BINT], n);
        int d0 = clampi(dst[i], n);
        int d1 = clampi(dst[i + BINT], n);
        int d2 = clampi(dst[i + 2 * BINT], n);
        int d3 = clampi(dst[i + 3 * BINT], n);
        int p0 = atomicAdd(&lcur[d0 >> BUCKSH], 1);
        int p1 = atomicAdd(&lcur[d1 >> BUCKSH], 1);
        int p2 = atomicAdd(&lcur[d2 >> BUCKSH], 1);
        int p3 = atomicAdd(&lcur[d3 >> BUCKSH], 1);
        bbuf[p0] = ((d0 & (BUCKN - 1)) << 18) | s0;
        bbuf[p1] = ((d1 & (BUCKN - 1)) << 18) | s1;
        bbuf[p2] = ((d2 & (BUCKN - 1)) << 18) | s2;
        bbuf[p3] = ((d3 & (BUCKN - 1)) << 18) | s3;
    }
    for (; i < end; i += BINT) {
        int s0 = clampi(src[i], n);
        int d0 = clampi(dst[i], n);
        int p0 = atomicAdd(&lcur[d0 >> BUCKSH], 1);
        bbuf[p0] = ((d0 & (BUCKN - 1)) << 18) | s0;
    }
}

// --- per-bucket counting sort on key=(dlow<<1)|srchalf; 8-way ILP --------
__global__ __launch_bounds__(1024) void k_bucket2(
    const int* __restrict__ bbuf, const int* __restrict__ bstart, int n, int h,
    int* __restrict__ rp2, float* __restrict__ dinv, int* __restrict__ adj) {
    __shared__ int lcnt[2048];
    __shared__ int wsum[16];
    const int b = blockIdx.x;
    const int t = threadIdx.x;
    const int start = bstart[b];
    const int end = bstart[b + 1];

    lcnt[t] = 0;
    lcnt[t + 1024] = 0;
    __syncthreads();
    {
        int i = start + t;
        for (; i + 7 * 1024 < end; i += 8 * 1024) {
            int p[8], k[8];
#pragma unroll
            for (int q = 0; q < 8; ++q) p[q] = bbuf[i + q * 1024];
#pragma unroll
            for (int q = 0; q < 8; ++q)
                k[q] = ((((unsigned)p[q]) >> 18) << 1) |
                       ((p[q] & 0x3FFFF) >= h);
#pragma unroll
            for (int q = 0; q < 8; ++q) atomicAdd(&lcnt[k[q]], 1);
        }
        for (; i < end; i += 1024) {
            int p = bbuf[i];
            int k = ((((unsigned)p) >> 18) << 1) | ((p & 0x3FFFF) >= h);
            atomicAdd(&lcnt[k], 1);
        }
    }
    __syncthreads();

    const int c0 = lcnt[2 * t];
    const int c1 = lcnt[2 * t + 1];
    const int psum = c0 + c1;
    int val = psum;
#pragma unroll
    for (int off = 1; off < 64; off <<= 1) {
        int vv = __shfl_up(val, off, 64);
        if ((t & 63) >= off) val += vv;
    }
    if ((t & 63) == 63) wsum[t >> 6] = val;
    __syncthreads();
    if (t == 0) {
        int run = 0;
#pragma unroll
        for (int w = 0; w < 16; ++w) {
            int v = wsum[w];
            wsum[w] = run;
            run += v;
        }
    }
    __syncthreads();
    const int exclPair = val + wsum[t >> 6] - psum;
    const int v = (b << BUCKSH) + t;
    if (v < n) {
        rp2[2 * v] = start + exclPair + c0;
        rp2[2 * v + 1] = start + exclPair + c0 + c1;
        dinv[v] = rsqrtf((float)(c0 + c1 + 1));
    }
    lcnt[2 * t] = start + exclPair;
    lcnt[2 * t + 1] = start + exclPair + c0;
    __syncthreads();

    {
        int i = start + t;
        for (; i + 7 * 1024 < end; i += 8 * 1024) {
            int p[8], k[8], q8[8];
#pragma unroll
            for (int q = 0; q < 8; ++q) p[q] = bbuf[i + q * 1024];
#pragma unroll
            for (int q = 0; q < 8; ++q)
                k[q] = ((((unsigned)p[q]) >> 18) << 1) |
                       ((p[q] & 0x3FFFF) >= h);
#pragma unroll
            for (int q = 0; q < 8; ++q) q8[q] = atomicAdd(&lcnt[k[q]], 1);
#pragma unroll
            for (int q = 0; q < 8; ++q) adj[q8[q]] = p[q] & 0x3FFFF;
        }
        for (; i < end; i += 1024) {
            int p = bbuf[i];
            int k = ((((unsigned)p) >> 18) << 1) | ((p & 0x3FFFF) >= h);
            int q = atomicAdd(&lcnt[k], 1);
            adj[q] = p & 0x3FFFF;
        }
    }
}

// --- h1s = dinv*(x@W1): LDS-staged tile, 16-ch fp16 table ----------------
__global__ __launch_bounds__(512) void k_mm1(const float* __restrict__ x,
                                             const float* __restrict__ W,
                                             const float* __restrict__ dinv,
                                             int n, __half* __restrict__ hs) {
    __shared__ float Ws[128 * 16];
    __shared__ float xs[MMN * 132];
    const int t = threadIdx.x;
    for (int i = t; i < 128 * 16; i += 512) Ws[i] = W[i];
    const int node0 = blockIdx.x * MMN;
    {
        const float4* xg = (const float4*)(x + (size_t)node0 * 128);
#pragma unroll
        for (int it = 0; it < 2; ++it) {
            int idx = it * 512 + t;
            int row = idx >> 5;
            int c4 = idx & 31;
            if (node0 + row < n) {
                float4 v = xg[(size_t)row * 32 + c4];
                float* dp = &xs[row * 132 + c4 * 4];
                dp[0] = v.x;
                dp[1] = v.y;
                dp[2] = v.z;
                dp[3] = v.w;
            }
        }
    }
    __syncthreads();
    const int node = node0 + (t >> 4);
    const int c = t & 15;
    if (node < n) {
        const float4* xr4 = (const float4*)&xs[(t >> 4) * 132];
        float acc = 0.f;
#pragma unroll
        for (int q = 0; q < 32; ++q) {
            float4 xv = xr4[q];
            acc += xv.x * Ws[(4 * q + 0) * 16 + c] +
                   xv.y * Ws[(4 * q + 1) * 16 + c] +
                   xv.z * Ws[(4 * q + 2) * 16 + c] +
                   xv.w * Ws[(4 * q + 3) * 16 + c];
        }
        hs[(size_t)node * 16 + c] = __float2half(dinv[node] * acc);
    }
}

__device__ __forceinline__ void unpack8(float4 r, float* f) {
    const __half2* hp = (const __half2*)&r;
#pragma unroll
    for (int q = 0; q < 4; ++q) {
        f[2 * q] = __low2float(hp[q]);
        f[2 * q + 1] = __high2float(hp[q]);
    }
}

// --- src-split gather. THREAD = NODE. 16 f32 accumulators. ---------------
// PASSA: acc=0, walk [rowstart, rp2[2v]) -> store f32 partial (64 B).
// PASSB: acc=partial, walk [rp2[2v], rp2[2v+1]), add self, finalize.
template <bool L1, bool PASSB>
__global__ void k_gn(const int* __restrict__ rp2,
                     const int* __restrict__ bstart,
                     const int* __restrict__ adj,
                     const float* __restrict__ dinv,
                     const __half* __restrict__ hs,
                     const float* __restrict__ bias,
                     float* __restrict__ partial, void* __restrict__ o,
                     int n) {
    int v = blockIdx.x * blockDim.x + threadIdx.x;
    int stride = gridDim.x * blockDim.x;
    for (; v < n; v += stride) {
        const int rowstart =
            ((v & (BUCKN - 1)) == 0) ? bstart[v >> BUCKSH] : rp2[2 * v - 1];
        const int s = PASSB ? rp2[2 * v] : rowstart;
        const int e = PASSB ? rp2[2 * v + 1] : rp2[2 * v];
        float acc[16];
        if (PASSB) {
            const float4* pp = (const float4*)(partial + (size_t)v * 16);
#pragma unroll
            for (int q = 0; q < 4; ++q) {
                float4 a = pp[q];
                acc[4 * q] = a.x;
                acc[4 * q + 1] = a.y;
                acc[4 * q + 2] = a.z;
                acc[4 * q + 3] = a.w;
            }
        } else {
#pragma unroll
            for (int q = 0; q < 16; ++q) acc[q] = 0.f;
        }
        int k = s;
        for (; k + 1 < e; k += 2) {
            int s0 = adj[k], s1 = adj[k + 1];
            const float4* r0 = (const float4*)(hs + (size_t)s0 * 16);
            const float4* r1 = (const float4*)(hs + (size_t)s1 * 16);
            float4 a0 = r0[0], b0 = r0[1];
            float4 a1 = r1[0], b1 = r1[1];
            float f[16];
            unpack8(a0, f);
            unpack8(b0, f + 8);
#pragma unroll
            for (int q = 0; q < 16; ++q) acc[q] += f[q];
            unpack8(a1, f);
            unpack8(b1, f + 8);
#pragma unroll
            for (int q = 0; q < 16; ++q) acc[q] += f[q];
        }
        if (k < e) {
            const float4* r0 = (const float4*)(hs + (size_t)adj[k] * 16);
            float4 a0 = r0[0], b0 = r0[1];
            float f[16];
            unpack8(a0, f);
            unpack8(b0, f + 8);
#pragma unroll
            for (int q = 0; q < 16; ++q) acc[q] += f[q];
        }
        if (!PASSB) {
            float* pp = partial + (size_t)v * 16;
#pragma unroll
            for (int q = 0; q < 4; ++q)
                *(float4*)(pp + 4 * q) =
                    make_float4(acc[4 * q], acc[4 * q + 1], acc[4 * q + 2],
                                acc[4 * q + 3]);
        } else {
            const float4* rs = (const float4*)(hs + (size_t)v * 16);
            float fs[16];
            unpack8(rs[0], fs);
            unpack8(rs[1], fs + 8);
            const float dv = dinv[v];
            if (L1) {
                __half2 hr[8];
#pragma unroll
                for (int q = 0; q < 8; ++q) {
                    float v0 = dv * fmaxf(dv * (acc[2 * q] + fs[2 * q]) +
                                              bias[2 * q],
                                          0.f);
                    float v1 =
                        dv * fmaxf(dv * (acc[2 * q + 1] + fs[2 * q + 1]) +
                                       bias[2 * q + 1],
                                   0.f);
                    hr[q] = __floats2half2_rn(v0, v1);
                }
                float4* op = (float4*)((__half*)o + (size_t)v * 16);
                op[0] = *(const float4*)hr;
                op[1] = *(const float4*)(hr + 4);
            } else {
                float* op = (float*)o + (size_t)v * 16;
#pragma unroll
                for (int q = 0; q < 4; ++q)
                    *(float4*)(op + 4 * q) = make_float4(
                        dv * (acc[4 * q] + fs[4 * q]),
                        dv * (acc[4 * q + 1] + fs[4 * q + 1]),
                        dv * (acc[4 * q + 2] + fs[4 * q + 2]),
                        dv * (acc[4 * q + 3] + fs[4 * q + 3]));
            }
        }
    }
}

// --- out = pre @ W2 + b2 --------------------------------------------------
__global__ void k_out(const float* __restrict__ pre,
                      const float* __restrict__ W2,
                      const float* __restrict__ b2, float* __restrict__ out,
                      int n) {
    __shared__ float Ws[16 * 32];
    for (int i = threadIdx.x; i < 16 * 32; i += blockDim.x) Ws[i] = W2[i];
    __syncthreads();
    long long total = (long long)n * 32;
    long long i = (long long)blockIdx.x * blockDim.x + threadIdx.x;
    long long stride = (long long)gridDim.x * blockDim.x;
    for (; i < total; i += stride) {
        int v = (int)(i >> 5);
        int c = (int)(i & 31);
        const float* pr = pre + (size_t)v * 16;
        float acc = b2[c];
#pragma unroll
        for (int j = 0; j < 16; ++j) acc += pr[j] * Ws[j * 32 + c];
        out[i] = acc;
    }
}

static inline int blocks_for(long long total) {
    return (int)((total + TPB - 1) / TPB);
}

extern "C" void kernel_launch(void* const* d_in, const int* in_sizes, int n_in,
                              void* d_out, int out_size, void* d_ws,
                              size_t ws_size, hipStream_t stream) {
    const float* x = (const float*)d_in[0];
    const int* ei = (const int*)d_in[1];
    const float* W1 = (const float*)d_in[2];
    const float* b1 = (const float*)d_in[3];
    const float* W2 = (const float*)d_in[4];
    const float* b2 = (const float*)d_in[5];
    float* out = (float*)d_out;

    const int n = in_sizes[0] / 128;  // 200000 nodes
    const int E = in_sizes[1] / 2;    // 6400000 edges
    const int* src = ei;
    const int* dst = ei + E;
    const int nbuck = (n + BUCKN - 1) / BUCKN;  // 196
    const int h = (n + 1) / 2;                  // src-half boundary

    char* ws = (char*)d_ws;
    float* dinv = (float*)ws;
    int* rp2 = (int*)(ws + (size_t)n * 4);
    int* adj = (int*)(ws + (size_t)n * 12);
    char* R = ws + (size_t)n * 12 + (size_t)E * 4;
    size_t base_bytes = (size_t)n * 12 + (size_t)E * 8;

    auto need = [&](int nbb) {
        return base_bytes +
               ((size_t)nbb + (size_t)nbb / SEGROWS + 2) * nbuck * 4 + 8192;
    };
    const int NBB =
        (ws_size >= need(2048)) ? 2048 : ((ws_size >= need(1024)) ? 1024 : 512);
    const int nseg = NBB / SEGROWS;
    const int chunk = (E + NBB - 1) / NBB;

    int* hist = (int*)(R + (size_t)E * 4);
    int* segsum = hist + (size_t)NBB * nbuck;
    int* colsum = segsum + (size_t)nseg * nbuck;
    int* bstart = colsum + nbuck;
    int* bbuf = (int*)R;

    __half* h1s = (__half*)R;
    __half* z1s = (__half*)(R + (size_t)n * 32);
    float* pre = (float*)(R + (size_t)n * 64);

    const int cb = (nbuck + 255) / 256;  // 1

    // --- build ---
    k_hist<<<NBB, BINT, 0, stream>>>(dst, E, n, nbuck, chunk, hist);
    k_scanA1<<<dim3(cb, nseg), 256, 0, stream>>>(hist, nbuck, segsum);
    k_scanA2<<<cb, 256, 0, stream>>>(segsum, nbuck, nseg, colsum);
    k_scanB<<<1, 256, 0, stream>>>(colsum, nbuck, E, bstart);
    k_scanA3<<<dim3(cb, nseg), 256, 0, stream>>>(hist, nbuck, segsum);
    k_bin<<<NBB, BINT, 0, stream>>>(src, dst, E, n, nbuck, chunk, hist, bstart,
                                    bbuf);
    k_bucket2<<<nbuck, 1024, 0, stream>>>(bbuf, bstart, n, h, rp2, dinv, adj);

    // --- layer 1 ---
    k_mm1<<<(n + MMN - 1) / MMN, 512, 0, stream>>>(x, W1, dinv, n, h1s);
    k_gn<true, false><<<blocks_for(n), TPB, 0, stream>>>(
        rp2, bstart, adj, dinv, h1s, b1, pre, nullptr, n);
    k_gn<true, true><<<blocks_for(n), TPB, 0, stream>>>(
        rp2, bstart, adj, dinv, h1s, b1, pre, z1s, n);

    // --- layer 2 ---
    k_gn<false, false><<<blocks_for(n), TPB, 0, stream>>>(
        rp2, bstart, adj, dinv, z1s, nullptr, pre, nullptr, n);
    k_gn<false, true><<<blocks_for(n), TPB, 0, stream>>>(
        rp2, bstart, adj, dinv, z1s, nullptr, pre, pre, n);

    k_out<<<blocks_for((long long)n * 32), TPB, 0, stream>>>(pre, W2, b2, out,
                                                             n);
}

// Round 19
// 330.931 us; speedup vs baseline: 1.3286x; 1.3286x over previous
//
#include <hip/hip_runtime.h>
#include <hip/hip_fp16.h>

// ---------------------------------------------------------------------------
// 2-layer GCN, CSR with rows sub-sorted by source-half (src<h | src>=h).
// Binding constraint (r16): random-gather hot set must fit per-XCD L2
// (4 MB). Source-split passes: pass A walks A-edges (table rows [0,h) =
// 3.2 MB hot), pass B walks B-edges (rows [h,n)), accumulating onto pass-A
// partials. 2 passes x E/2 edges per layer.
//   build: k_hist -> scans -> k_bin (1024-node buckets)
//          k_bucket2: within-bucket counting sort, key=(dlow<<1)|srchalf.
//          SCATTER IS PASS-SPLIT into 4 key-range passes: active write
//          window 512 lines/block (~2 MB/XCD) so lines fill before eviction
//          (r18 counters: single-pass scatter = 235 MB HBM writes for a
//          25.6 MB adj, 9x RMW amplification, 46% of HBM peak).
//   L1: k_mm1 (h1s = dinv*(x@W1), fp16 n x 16) ; gnA -> partial(f32) ;
//       gnB -> z1s = dinv*relu(dinv*(agg+self)+b1) (fp16)
//   L2: gnA(z1s) -> pre ; gnB -> pre (f32, in place)
//   k_out: out = pre @ W2 + b2
// k_gn: thread = (node, row-half) (r17 form; r18's thread=node halved
// occupancy to 3 blocks/CU and regressed 24%). 4-edge unroll, 8 f32 acc.
// Region R = bbuf then {h1s,z1s,pre}. Packing needs n < 2^18 (200000 ok).
// ---------------------------------------------------------------------------

#define TPB 256
#define BINT 256
#define SEGROWS 64
#define BUCKSH 10
#define BUCKN (1 << BUCKSH)
#define MMN 32

__device__ __forceinline__ int clampi(int v, int n) {
    return v < 0 ? 0 : (v >= n ? n - 1 : v);
}

// --- per-block LDS histogram over contiguous edge range ------------------
__global__ __launch_bounds__(BINT) void k_hist(const int* __restrict__ dst,
                                               int E, int n, int nbuck,
                                               int chunk,
                                               int* __restrict__ hist) {
    __shared__ int lh[256];
    const int b = blockIdx.x;
    const int t = threadIdx.x;
    lh[t] = 0;
    __syncthreads();
    const int start = b * chunk;
    const int end = min(E, start + chunk);
    int i = start + t;
    for (; i + 3 * BINT < end; i += 4 * BINT) {
        int d0 = clampi(dst[i], n);
        int d1 = clampi(dst[i + BINT], n);
        int d2 = clampi(dst[i + 2 * BINT], n);
        int d3 = clampi(dst[i + 3 * BINT], n);
        atomicAdd(&lh[d0 >> BUCKSH], 1);
        atomicAdd(&lh[d1 >> BUCKSH], 1);
        atomicAdd(&lh[d2 >> BUCKSH], 1);
        atomicAdd(&lh[d3 >> BUCKSH], 1);
    }
    for (; i < end; i += BINT) atomicAdd(&lh[clampi(dst[i], n) >> BUCKSH], 1);
    __syncthreads();
    for (int k = t; k < nbuck; k += BINT) hist[b * nbuck + k] = lh[k];
}

// --- segmented column scan stage 1 ---------------------------------------
__global__ void k_scanA1(const int* __restrict__ hist, int nbuck,
                         int* __restrict__ segsum) {
    int k = blockIdx.x * blockDim.x + threadIdx.x;
    int seg = blockIdx.y;
    if (k >= nbuck) return;
    const int* row = hist + (size_t)seg * SEGROWS * nbuck + k;
    int sum = 0;
#pragma unroll
    for (int b = 0; b < SEGROWS; ++b) sum += row[(size_t)b * nbuck];
    segsum[seg * nbuck + k] = sum;
}

// --- stage 2 --------------------------------------------------------------
__global__ void k_scanA2(int* __restrict__ segsum, int nbuck, int nseg,
                         int* __restrict__ colsum) {
    int k = blockIdx.x * blockDim.x + threadIdx.x;
    if (k >= nbuck) return;
    int run = 0;
    for (int sg = 0; sg < nseg; ++sg) {
        int v = segsum[sg * nbuck + k];
        segsum[sg * nbuck + k] = run;
        run += v;
    }
    colsum[k] = run;
}

// --- exclusive scan of colsum -> bstart ----------------------------------
__global__ void k_scanB(const int* __restrict__ colsum, int nbuck, int E,
                        int* __restrict__ bstart) {
    __shared__ int s[256];
    const int t = threadIdx.x;
    int loc[4];
    int a = 0;
#pragma unroll
    for (int i = 0; i < 4; ++i) {
        int idx = 4 * t + i;
        loc[i] = (idx < nbuck) ? colsum[idx] : 0;
        a += loc[i];
    }
    s[t] = a;
    __syncthreads();
#pragma unroll
    for (int off = 1; off < 256; off <<= 1) {
        int v = (t >= off) ? s[t - off] : 0;
        __syncthreads();
        s[t] += v;
        __syncthreads();
    }
    int base = s[t] - a;
#pragma unroll
    for (int i = 0; i < 4; ++i) {
        int idx = 4 * t + i;
        if (idx < nbuck) bstart[idx] = base;
        base += loc[i];
    }
    if (t == 255) bstart[nbuck] = E;
}

// --- stage 3 --------------------------------------------------------------
__global__ void k_scanA3(int* __restrict__ hist, int nbuck,
                         const int* __restrict__ segsum) {
    int k = blockIdx.x * blockDim.x + threadIdx.x;
    int seg = blockIdx.y;
    if (k >= nbuck) return;
    int run = segsum[seg * nbuck + k];
    int* row = hist + (size_t)seg * SEGROWS * nbuck + k;
#pragma unroll
    for (int b = 0; b < SEGROWS; ++b) {
        int v = row[(size_t)b * nbuck];
        row[(size_t)b * nbuck] = run;
        run += v;
    }
}

// --- binning: LDS cursors; 4-way ILP -------------------------------------
__global__ __launch_bounds__(BINT) void k_bin(const int* __restrict__ src,
                                              const int* __restrict__ dst,
                                              int E, int n, int nbuck,
                                              int chunk,
                                              const int* __restrict__ hist,
                                              const int* __restrict__ bstart,
                                              int* __restrict__ bbuf) {
    __shared__ int lcur[256];
    const int b = blockIdx.x;
    const int t = threadIdx.x;
    for (int k = t; k < nbuck; k += BINT)
        lcur[k] = bstart[k] + hist[b * nbuck + k];
    __syncthreads();
    const int start = b * chunk;
    const int end = min(E, start + chunk);
    int i = start + t;
    for (; i + 3 * BINT < end; i += 4 * BINT) {
        int s0 = clampi(src[i], n);
        int s1 = clampi(src[i + BINT], n);
        int s2 = clampi(src[i + 2 * BINT], n);
        int s3 = clampi(src[i + 3 * BINT], n);
        int d0 = clampi(dst[i], n);
        int d1 = clampi(dst[i + BINT], n);
        int d2 = clampi(dst[i + 2 * BINT], n);
        int d3 = clampi(dst[i + 3 * BINT], n);
        int p0 = atomicAdd(&lcur[d0 >> BUCKSH], 1);
        int p1 = atomicAdd(&lcur[d1 >> BUCKSH], 1);
        int p2 = atomicAdd(&lcur[d2 >> BUCKSH], 1);
        int p3 = atomicAdd(&lcur[d3 >> BUCKSH], 1);
        bbuf[p0] = ((d0 & (BUCKN - 1)) << 18) | s0;
        bbuf[p1] = ((d1 & (BUCKN - 1)) << 18) | s1;
        bbuf[p2] = ((d2 & (BUCKN - 1)) << 18) | s2;
        bbuf[p3] = ((d3 & (BUCKN - 1)) << 18) | s3;
    }
    for (; i < end; i += BINT) {
        int s0 = clampi(src[i], n);
        int d0 = clampi(dst[i], n);
        int p0 = atomicAdd(&lcur[d0 >> BUCKSH], 1);
        bbuf[p0] = ((d0 & (BUCKN - 1)) << 18) | s0;
    }
}

// --- per-bucket counting sort, key=(dlow<<1)|srchalf; PASS-SPLIT scatter -
__global__ __launch_bounds__(1024) void k_bucket2(
    const int* __restrict__ bbuf, const int* __restrict__ bstart, int n, int h,
    int* __restrict__ rp2, float* __restrict__ dinv, int* __restrict__ adj) {
    __shared__ int lcnt[2048];
    __shared__ int wsum[16];
    const int b = blockIdx.x;
    const int t = threadIdx.x;
    const int start = bstart[b];
    const int end = bstart[b + 1];

    lcnt[t] = 0;
    lcnt[t + 1024] = 0;
    __syncthreads();
    {
        int i = start + t;
        for (; i + 7 * 1024 < end; i += 8 * 1024) {
            int p[8], k[8];
#pragma unroll
            for (int q = 0; q < 8; ++q) p[q] = bbuf[i + q * 1024];
#pragma unroll
            for (int q = 0; q < 8; ++q)
                k[q] = ((((unsigned)p[q]) >> 18) << 1) |
                       ((p[q] & 0x3FFFF) >= h);
#pragma unroll
            for (int q = 0; q < 8; ++q) atomicAdd(&lcnt[k[q]], 1);
        }
        for (; i < end; i += 1024) {
            int p = bbuf[i];
            int k = ((((unsigned)p) >> 18) << 1) | ((p & 0x3FFFF) >= h);
            atomicAdd(&lcnt[k], 1);
        }
    }
    __syncthreads();

    const int c0 = lcnt[2 * t];
    const int c1 = lcnt[2 * t + 1];
    const int psum = c0 + c1;
    int val = psum;
#pragma unroll
    for (int off = 1; off < 64; off <<= 1) {
        int vv = __shfl_up(val, off, 64);
        if ((t & 63) >= off) val += vv;
    }
    if ((t & 63) == 63) wsum[t >> 6] = val;
    __syncthreads();
    if (t == 0) {
        int run = 0;
#pragma unroll
        for (int w = 0; w < 16; ++w) {
            int v = wsum[w];
            wsum[w] = run;
            run += v;
        }
    }
    __syncthreads();
    const int exclPair = val + wsum[t >> 6] - psum;
    const int v = (b << BUCKSH) + t;
    if (v < n) {
        rp2[2 * v] = start + exclPair + c0;
        rp2[2 * v + 1] = start + exclPair + c0 + c1;
        dinv[v] = rsqrtf((float)(c0 + c1 + 1));
    }
    lcnt[2 * t] = start + exclPair;
    lcnt[2 * t + 1] = start + exclPair + c0;
    __syncthreads();

    // pass-split scatter: 4 key-range passes keep the active write window
    // at 512 lines/block (~2 MB/XCD) so lines fill before L2 eviction.
#pragma unroll 1
    for (int p4 = 0; p4 < 4; ++p4) {
        const int keylo = p4 << 9;
        const int keyhi = keylo + 512;
        int i = start + t;
        for (; i + 3 * 1024 < end; i += 4 * 1024) {
            int p[4], k[4];
#pragma unroll
            for (int q = 0; q < 4; ++q) p[q] = bbuf[i + q * 1024];
#pragma unroll
            for (int q = 0; q < 4; ++q)
                k[q] = ((((unsigned)p[q]) >> 18) << 1) |
                       ((p[q] & 0x3FFFF) >= h);
#pragma unroll
            for (int q = 0; q < 4; ++q) {
                if (k[q] >= keylo && k[q] < keyhi) {
                    int pos = atomicAdd(&lcnt[k[q]], 1);
                    adj[pos] = p[q] & 0x3FFFF;
                }
            }
        }
        for (; i < end; i += 1024) {
            int p = bbuf[i];
            int k = ((((unsigned)p) >> 18) << 1) | ((p & 0x3FFFF) >= h);
            if (k >= keylo && k < keyhi) {
                int pos = atomicAdd(&lcnt[k], 1);
                adj[pos] = p & 0x3FFFF;
            }
        }
        __syncthreads();
    }
}

// --- h1s = dinv*(x@W1): LDS-staged tile, 16-ch fp16 table ----------------
__global__ __launch_bounds__(512) void k_mm1(const float* __restrict__ x,
                                             const float* __restrict__ W,
                                             const float* __restrict__ dinv,
                                             int n, __half* __restrict__ hs) {
    __shared__ float Ws[128 * 16];
    __shared__ float xs[MMN * 132];
    const int t = threadIdx.x;
    for (int i = t; i < 128 * 16; i += 512) Ws[i] = W[i];
    const int node0 = blockIdx.x * MMN;
    {
        const float4* xg = (const float4*)(x + (size_t)node0 * 128);
#pragma unroll
        for (int it = 0; it < 2; ++it) {
            int idx = it * 512 + t;
            int row = idx >> 5;
            int c4 = idx & 31;
            if (node0 + row < n) {
                float4 v = xg[(size_t)row * 32 + c4];
                float* dp = &xs[row * 132 + c4 * 4];
                dp[0] = v.x;
                dp[1] = v.y;
                dp[2] = v.z;
                dp[3] = v.w;
            }
        }
    }
    __syncthreads();
    const int node = node0 + (t >> 4);
    const int c = t & 15;
    if (node < n) {
        const float4* xr4 = (const float4*)&xs[(t >> 4) * 132];
        float acc = 0.f;
#pragma unroll
        for (int q = 0; q < 32; ++q) {
            float4 xv = xr4[q];
            acc += xv.x * Ws[(4 * q + 0) * 16 + c] +
                   xv.y * Ws[(4 * q + 1) * 16 + c] +
                   xv.z * Ws[(4 * q + 2) * 16 + c] +
                   xv.w * Ws[(4 * q + 3) * 16 + c];
        }
        hs[(size_t)node * 16 + c] = __float2half(dinv[node] * acc);
    }
}

__device__ __forceinline__ void unpack8(float4 r, float* f) {
    const __half2* hp = (const __half2*)&r;
#pragma unroll
    for (int q = 0; q < 4; ++q) {
        f[2 * q] = __low2float(hp[q]);
        f[2 * q + 1] = __high2float(hp[q]);
    }
}

// --- src-split gather. thread = (node, row-half). 8 f32 accumulators. ----
template <bool L1, bool PASSB>
__global__ void k_gn(const int* __restrict__ rp2,
                     const int* __restrict__ bstart,
                     const int* __restrict__ adj,
                     const float* __restrict__ dinv,
                     const __half* __restrict__ hs,
                     const float* __restrict__ bias,
                     float* __restrict__ partial, void* __restrict__ o,
                     int n) {
    long long total = 2LL * n;
    long long i = (long long)blockIdx.x * blockDim.x + threadIdx.x;
    long long stride = (long long)gridDim.x * blockDim.x;
    for (; i < total; i += stride) {
        const int v = (int)(i >> 1);
        const int hf = (int)(i & 1);
        const int rowstart =
            ((v & (BUCKN - 1)) == 0) ? bstart[v >> BUCKSH] : rp2[2 * v - 1];
        const int s = PASSB ? rp2[2 * v] : rowstart;
        const int e = PASSB ? rp2[2 * v + 1] : rp2[2 * v];
        float acc[8];
        if (PASSB) {
            const float4* pp =
                (const float4*)(partial + (size_t)v * 16 + hf * 8);
            float4 a = pp[0], b = pp[1];
            acc[0] = a.x; acc[1] = a.y; acc[2] = a.z; acc[3] = a.w;
            acc[4] = b.x; acc[5] = b.y; acc[6] = b.z; acc[7] = b.w;
        } else {
#pragma unroll
            for (int q = 0; q < 8; ++q) acc[q] = 0.f;
        }
        int k = s;
        for (; k + 3 < e; k += 4) {
            int s0 = adj[k], s1 = adj[k + 1], s2 = adj[k + 2], s3 = adj[k + 3];
            float4 r0 = *(const float4*)(hs + (size_t)s0 * 16 + hf * 8);
            float4 r1 = *(const float4*)(hs + (size_t)s1 * 16 + hf * 8);
            float4 r2 = *(const float4*)(hs + (size_t)s2 * 16 + hf * 8);
            float4 r3 = *(const float4*)(hs + (size_t)s3 * 16 + hf * 8);
            float f0[8], f1[8], f2[8], f3[8];
            unpack8(r0, f0);
            unpack8(r1, f1);
            unpack8(r2, f2);
            unpack8(r3, f3);
#pragma unroll
            for (int q = 0; q < 8; ++q)
                acc[q] += (f0[q] + f1[q]) + (f2[q] + f3[q]);
        }
        for (; k < e; ++k) {
            float4 r = *(const float4*)(hs + (size_t)adj[k] * 16 + hf * 8);
            float f[8];
            unpack8(r, f);
#pragma unroll
            for (int q = 0; q < 8; ++q) acc[q] += f[q];
        }
        if (!PASSB) {
            float* pp = partial + (size_t)v * 16 + hf * 8;
            *(float4*)pp = make_float4(acc[0], acc[1], acc[2], acc[3]);
            *(float4*)(pp + 4) = make_float4(acc[4], acc[5], acc[6], acc[7]);
        } else {
            float4 rs = *(const float4*)(hs + (size_t)v * 16 + hf * 8);
            float fs[8];
            unpack8(rs, fs);
            const float dv = dinv[v];
            if (L1) {
                __half2 hr[4];
#pragma unroll
                for (int q = 0; q < 4; ++q) {
                    float v0 = dv * fmaxf(dv * (acc[2 * q] + fs[2 * q]) +
                                              bias[hf * 8 + 2 * q],
                                          0.f);
                    float v1 = dv * fmaxf(dv * (acc[2 * q + 1] + fs[2 * q + 1]) +
                                              bias[hf * 8 + 2 * q + 1],
                                          0.f);
                    hr[q] = __floats2half2_rn(v0, v1);
                }
                *(float4*)((__half*)o + (size_t)v * 16 + hf * 8) =
                    *(const float4*)hr;
            } else {
                float* op = (float*)o + (size_t)v * 16 + hf * 8;
                *(float4*)op =
                    make_float4(dv * (acc[0] + fs[0]), dv * (acc[1] + fs[1]),
                                dv * (acc[2] + fs[2]), dv * (acc[3] + fs[3]));
                *(float4*)(op + 4) =
                    make_float4(dv * (acc[4] + fs[4]), dv * (acc[5] + fs[5]),
                                dv * (acc[6] + fs[6]), dv * (acc[7] + fs[7]));
            }
        }
    }
}

// --- out = pre @ W2 + b2 --------------------------------------------------
__global__ void k_out(const float* __restrict__ pre,
                      const float* __restrict__ W2,
                      const float* __restrict__ b2, float* __restrict__ out,
                      int n) {
    __shared__ float Ws[16 * 32];
    for (int i = threadIdx.x; i < 16 * 32; i += blockDim.x) Ws[i] = W2[i];
    __syncthreads();
    long long total = (long long)n * 32;
    long long i = (long long)blockIdx.x * blockDim.x + threadIdx.x;
    long long stride = (long long)gridDim.x * blockDim.x;
    for (; i < total; i += stride) {
        int v = (int)(i >> 5);
        int c = (int)(i & 31);
        const float* pr = pre + (size_t)v * 16;
        float acc = b2[c];
#pragma unroll
        for (int j = 0; j < 16; ++j) acc += pr[j] * Ws[j * 32 + c];
        out[i] = acc;
    }
}

static inline int blocks_for(long long total) {
    return (int)((total + TPB - 1) / TPB);
}

extern "C" void kernel_launch(void* const* d_in, const int* in_sizes, int n_in,
                              void* d_out, int out_size, void* d_ws,
                              size_t ws_size, hipStream_t stream) {
    const float* x = (const float*)d_in[0];
    const int* ei = (const int*)d_in[1];
    const float* W1 = (const float*)d_in[2];
    const float* b1 = (const float*)d_in[3];
    const float* W2 = (const float*)d_in[4];
    const float* b2 = (const float*)d_in[5];
    float* out = (float*)d_out;

    const int n = in_sizes[0] / 128;  // 200000 nodes
    const int E = in_sizes[1] / 2;    // 6400000 edges
    const int* src = ei;
    const int* dst = ei + E;
    const int nbuck = (n + BUCKN - 1) / BUCKN;  // 196
    const int h = (n + 1) / 2;                  // src-half boundary

    char* ws = (char*)d_ws;
    float* dinv = (float*)ws;
    int* rp2 = (int*)(ws + (size_t)n * 4);
    int* adj = (int*)(ws + (size_t)n * 12);
    char* R = ws + (size_t)n * 12 + (size_t)E * 4;
    size_t base_bytes = (size_t)n * 12 + (size_t)E * 8;

    auto need = [&](int nbb) {
        return base_bytes +
               ((size_t)nbb + (size_t)nbb / SEGROWS + 2) * nbuck * 4 + 8192;
    };
    const int NBB =
        (ws_size >= need(2048)) ? 2048 : ((ws_size >= need(1024)) ? 1024 : 512);
    const int nseg = NBB / SEGROWS;
    const int chunk = (E + NBB - 1) / NBB;

    int* hist = (int*)(R + (size_t)E * 4);
    int* segsum = hist + (size_t)NBB * nbuck;
    int* colsum = segsum + (size_t)nseg * nbuck;
    int* bstart = colsum + nbuck;
    int* bbuf = (int*)R;

    __half* h1s = (__half*)R;
    __half* z1s = (__half*)(R + (size_t)n * 32);
    float* pre = (float*)(R + (size_t)n * 64);

    const int cb = (nbuck + 255) / 256;  // 1

    // --- build ---
    k_hist<<<NBB, BINT, 0, stream>>>(dst, E, n, nbuck, chunk, hist);
    k_scanA1<<<dim3(cb, nseg), 256, 0, stream>>>(hist, nbuck, segsum);
    k_scanA2<<<cb, 256, 0, stream>>>(segsum, nbuck, nseg, colsum);
    k_scanB<<<1, 256, 0, stream>>>(colsum, nbuck, E, bstart);
    k_scanA3<<<dim3(cb, nseg), 256, 0, stream>>>(hist, nbuck, segsum);
    k_bin<<<NBB, BINT, 0, stream>>>(src, dst, E, n, nbuck, chunk, hist, bstart,
                                    bbuf);
    k_bucket2<<<nbuck, 1024, 0, stream>>>(bbuf, bstart, n, h, rp2, dinv, adj);

    // --- layer 1 ---
    k_mm1<<<(n + MMN - 1) / MMN, 512, 0, stream>>>(x, W1, dinv, n, h1s);
    k_gn<true, false><<<blocks_for(2LL * n), TPB, 0, stream>>>(
        rp2, bstart, adj, dinv, h1s, b1, pre, nullptr, n);
    k_gn<true, true><<<blocks_for(2LL * n), TPB, 0, stream>>>(
        rp2, bstart, adj, dinv, h1s, b1, pre, z1s, n);

    // --- layer 2 ---
    k_gn<false, false><<<blocks_for(2LL * n), TPB, 0, stream>>>(
        rp2, bstart, adj, dinv, z1s, nullptr, pre, nullptr, n);
    k_gn<false, true><<<blocks_for(2LL * n), TPB, 0, stream>>>(
        rp2, bstart, adj, dinv, z1s, nullptr, pre, pre, n);

    k_out<<<blocks_for((long long)n * 32), TPB, 0, stream>>>(pre, W2, b2, out,
                                                             n);
}

// Round 20
// 307.630 us; speedup vs baseline: 1.4293x; 1.0757x over previous
//
#include <hip/hip_runtime.h>
#include <hip/hip_fp16.h>

// ---------------------------------------------------------------------------
// 2-layer GCN, CSR with rows sub-sorted by source-half (src<h | src>=h).
// Binding constraint (r16): random-gather hot set must fit per-XCD L2
// (4 MB). Source-split passes: pass A walks A-edges (table rows [0,h) =
// 3.2 MB hot), pass B walks B-edges (rows [h,n)), accumulating onto pass-A
// partials. 2 passes x E/2 edges per layer; 2E 16B-transactions per layer
// (invariant for 32 B rows) -> gathers run near L2 transaction rate.
//   build: k_hist -> scans -> k_bin (1024-node buckets, int4 edge reads)
//          k_bucket2: within-bucket counting sort, key=(dlow<<1)|srchalf,
//          pass-split scatter (4 key-range passes, r19: fixed 9x write amp)
//   L1: k_mm1 (h1s = dinv*(x@W1), fp16 n x 16) ; gnA -> partial(f32) ;
//       gnB -> z1s = dinv*relu(dinv*(agg+self)+b1) (fp16)
//   L2: gnA(z1s) -> pre ; gnB -> pre (f32, in place)
//   k_out: out = pre @ W2 + b2
// k_gn: thread = (node, row-half), 8-edge unroll (8 row-loads in flight).
// chunk rounded to x4 so int4 edge loads stay 16 B aligned.
// Region R = bbuf then {h1s,z1s,pre}. Packing needs n < 2^18 (200000 ok).
// ---------------------------------------------------------------------------

#define TPB 256
#define BINT 256
#define SEGROWS 64
#define BUCKSH 10
#define BUCKN (1 << BUCKSH)
#define MMN 32

__device__ __forceinline__ int clampi(int v, int n) {
    return v < 0 ? 0 : (v >= n ? n - 1 : v);
}

// --- per-block LDS histogram over contiguous edge range (int4 reads) -----
__global__ __launch_bounds__(BINT) void k_hist(const int* __restrict__ dst,
                                               int E, int n, int nbuck,
                                               int chunk,
                                               int* __restrict__ hist) {
    __shared__ int lh[256];
    const int b = blockIdx.x;
    const int t = threadIdx.x;
    lh[t] = 0;
    __syncthreads();
    const int start = b * chunk;
    const int end = min(E, start + chunk);
    for (int i = start + 4 * t; i < end; i += 4 * BINT) {
        if (i + 4 <= end) {
            int4 d4 = *(const int4*)(dst + i);
            atomicAdd(&lh[clampi(d4.x, n) >> BUCKSH], 1);
            atomicAdd(&lh[clampi(d4.y, n) >> BUCKSH], 1);
            atomicAdd(&lh[clampi(d4.z, n) >> BUCKSH], 1);
            atomicAdd(&lh[clampi(d4.w, n) >> BUCKSH], 1);
        } else {
            for (int j = i; j < end; ++j)
                atomicAdd(&lh[clampi(dst[j], n) >> BUCKSH], 1);
        }
    }
    __syncthreads();
    for (int k = t; k < nbuck; k += BINT) hist[b * nbuck + k] = lh[k];
}

// --- segmented column scan stage 1 ---------------------------------------
__global__ void k_scanA1(const int* __restrict__ hist, int nbuck,
                         int* __restrict__ segsum) {
    int k = blockIdx.x * blockDim.x + threadIdx.x;
    int seg = blockIdx.y;
    if (k >= nbuck) return;
    const int* row = hist + (size_t)seg * SEGROWS * nbuck + k;
    int sum = 0;
#pragma unroll
    for (int b = 0; b < SEGROWS; ++b) sum += row[(size_t)b * nbuck];
    segsum[seg * nbuck + k] = sum;
}

// --- stage 2 --------------------------------------------------------------
__global__ void k_scanA2(int* __restrict__ segsum, int nbuck, int nseg,
                         int* __restrict__ colsum) {
    int k = blockIdx.x * blockDim.x + threadIdx.x;
    if (k >= nbuck) return;
    int run = 0;
    for (int sg = 0; sg < nseg; ++sg) {
        int v = segsum[sg * nbuck + k];
        segsum[sg * nbuck + k] = run;
        run += v;
    }
    colsum[k] = run;
}

// --- exclusive scan of colsum -> bstart ----------------------------------
__global__ void k_scanB(const int* __restrict__ colsum, int nbuck, int E,
                        int* __restrict__ bstart) {
    __shared__ int s[256];
    const int t = threadIdx.x;
    int loc[4];
    int a = 0;
#pragma unroll
    for (int i = 0; i < 4; ++i) {
        int idx = 4 * t + i;
        loc[i] = (idx < nbuck) ? colsum[idx] : 0;
        a += loc[i];
    }
    s[t] = a;
    __syncthreads();
#pragma unroll
    for (int off = 1; off < 256; off <<= 1) {
        int v = (t >= off) ? s[t - off] : 0;
        __syncthreads();
        s[t] += v;
        __syncthreads();
    }
    int base = s[t] - a;
#pragma unroll
    for (int i = 0; i < 4; ++i) {
        int idx = 4 * t + i;
        if (idx < nbuck) bstart[idx] = base;
        base += loc[i];
    }
    if (t == 255) bstart[nbuck] = E;
}

// --- stage 3 --------------------------------------------------------------
__global__ void k_scanA3(int* __restrict__ hist, int nbuck,
                         const int* __restrict__ segsum) {
    int k = blockIdx.x * blockDim.x + threadIdx.x;
    int seg = blockIdx.y;
    if (k >= nbuck) return;
    int run = segsum[seg * nbuck + k];
    int* row = hist + (size_t)seg * SEGROWS * nbuck + k;
#pragma unroll
    for (int b = 0; b < SEGROWS; ++b) {
        int v = row[(size_t)b * nbuck];
        row[(size_t)b * nbuck] = run;
        run += v;
    }
}

// --- binning: LDS cursors; int4 edge reads, 4-way ILP --------------------
__global__ __launch_bounds__(BINT) void k_bin(const int* __restrict__ src,
                                              const int* __restrict__ dst,
                                              int E, int n, int nbuck,
                                              int chunk,
                                              const int* __restrict__ hist,
                                              const int* __restrict__ bstart,
                                              int* __restrict__ bbuf) {
    __shared__ int lcur[256];
    const int b = blockIdx.x;
    const int t = threadIdx.x;
    for (int k = t; k < nbuck; k += BINT)
        lcur[k] = bstart[k] + hist[b * nbuck + k];
    __syncthreads();
    const int start = b * chunk;
    const int end = min(E, start + chunk);
    for (int i = start + 4 * t; i < end; i += 4 * BINT) {
        if (i + 4 <= end) {
            int4 s4 = *(const int4*)(src + i);
            int4 d4 = *(const int4*)(dst + i);
            int s0 = clampi(s4.x, n), s1 = clampi(s4.y, n);
            int s2 = clampi(s4.z, n), s3 = clampi(s4.w, n);
            int d0 = clampi(d4.x, n), d1 = clampi(d4.y, n);
            int d2 = clampi(d4.z, n), d3 = clampi(d4.w, n);
            int p0 = atomicAdd(&lcur[d0 >> BUCKSH], 1);
            int p1 = atomicAdd(&lcur[d1 >> BUCKSH], 1);
            int p2 = atomicAdd(&lcur[d2 >> BUCKSH], 1);
            int p3 = atomicAdd(&lcur[d3 >> BUCKSH], 1);
            bbuf[p0] = ((d0 & (BUCKN - 1)) << 18) | s0;
            bbuf[p1] = ((d1 & (BUCKN - 1)) << 18) | s1;
            bbuf[p2] = ((d2 & (BUCKN - 1)) << 18) | s2;
            bbuf[p3] = ((d3 & (BUCKN - 1)) << 18) | s3;
        } else {
            for (int j = i; j < end; ++j) {
                int s0 = clampi(src[j], n);
                int d0 = clampi(dst[j], n);
                int p0 = atomicAdd(&lcur[d0 >> BUCKSH], 1);
                bbuf[p0] = ((d0 & (BUCKN - 1)) << 18) | s0;
            }
        }
    }
}

// --- per-bucket counting sort, key=(dlow<<1)|srchalf; PASS-SPLIT scatter -
__global__ __launch_bounds__(1024) void k_bucket2(
    const int* __restrict__ bbuf, const int* __restrict__ bstart, int n, int h,
    int* __restrict__ rp2, float* __restrict__ dinv, int* __restrict__ adj) {
    __shared__ int lcnt[2048];
    __shared__ int wsum[16];
    const int b = blockIdx.x;
    const int t = threadIdx.x;
    const int start = bstart[b];
    const int end = bstart[b + 1];

    lcnt[t] = 0;
    lcnt[t + 1024] = 0;
    __syncthreads();
    {
        int i = start + t;
        for (; i + 7 * 1024 < end; i += 8 * 1024) {
            int p[8], k[8];
#pragma unroll
            for (int q = 0; q < 8; ++q) p[q] = bbuf[i + q * 1024];
#pragma unroll
            for (int q = 0; q < 8; ++q)
                k[q] = ((((unsigned)p[q]) >> 18) << 1) |
                       ((p[q] & 0x3FFFF) >= h);
#pragma unroll
            for (int q = 0; q < 8; ++q) atomicAdd(&lcnt[k[q]], 1);
        }
        for (; i < end; i += 1024) {
            int p = bbuf[i];
            int k = ((((unsigned)p) >> 18) << 1) | ((p & 0x3FFFF) >= h);
            atomicAdd(&lcnt[k], 1);
        }
    }
    __syncthreads();

    const int c0 = lcnt[2 * t];
    const int c1 = lcnt[2 * t + 1];
    const int psum = c0 + c1;
    int val = psum;
#pragma unroll
    for (int off = 1; off < 64; off <<= 1) {
        int vv = __shfl_up(val, off, 64);
        if ((t & 63) >= off) val += vv;
    }
    if ((t & 63) == 63) wsum[t >> 6] = val;
    __syncthreads();
    if (t == 0) {
        int run = 0;
#pragma unroll
        for (int w = 0; w < 16; ++w) {
            int v = wsum[w];
            wsum[w] = run;
            run += v;
        }
    }
    __syncthreads();
    const int exclPair = val + wsum[t >> 6] - psum;
    const int v = (b << BUCKSH) + t;
    if (v < n) {
        rp2[2 * v] = start + exclPair + c0;
        rp2[2 * v + 1] = start + exclPair + c0 + c1;
        dinv[v] = rsqrtf((float)(c0 + c1 + 1));
    }
    lcnt[2 * t] = start + exclPair;
    lcnt[2 * t + 1] = start + exclPair + c0;
    __syncthreads();

    // 4 key-range passes keep the active write window at 512 lines/block.
#pragma unroll 1
    for (int p4 = 0; p4 < 4; ++p4) {
        const int keylo = p4 << 9;
        const int keyhi = keylo + 512;
        int i = start + t;
        for (; i + 3 * 1024 < end; i += 4 * 1024) {
            int p[4], k[4];
#pragma unroll
            for (int q = 0; q < 4; ++q) p[q] = bbuf[i + q * 1024];
#pragma unroll
            for (int q = 0; q < 4; ++q)
                k[q] = ((((unsigned)p[q]) >> 18) << 1) |
                       ((p[q] & 0x3FFFF) >= h);
#pragma unroll
            for (int q = 0; q < 4; ++q) {
                if (k[q] >= keylo && k[q] < keyhi) {
                    int pos = atomicAdd(&lcnt[k[q]], 1);
                    adj[pos] = p[q] & 0x3FFFF;
                }
            }
        }
        for (; i < end; i += 1024) {
            int p = bbuf[i];
            int k = ((((unsigned)p) >> 18) << 1) | ((p & 0x3FFFF) >= h);
            if (k >= keylo && k < keyhi) {
                int pos = atomicAdd(&lcnt[k], 1);
                adj[pos] = p & 0x3FFFF;
            }
        }
        __syncthreads();
    }
}

// --- h1s = dinv*(x@W1): LDS-staged tile, 16-ch fp16 table ----------------
__global__ __launch_bounds__(512) void k_mm1(const float* __restrict__ x,
                                             const float* __restrict__ W,
                                             const float* __restrict__ dinv,
                                             int n, __half* __restrict__ hs) {
    __shared__ float Ws[128 * 16];
    __shared__ float xs[MMN * 132];
    const int t = threadIdx.x;
    for (int i = t; i < 128 * 16; i += 512) Ws[i] = W[i];
    const int node0 = blockIdx.x * MMN;
    {
        const float4* xg = (const float4*)(x + (size_t)node0 * 128);
#pragma unroll
        for (int it = 0; it < 2; ++it) {
            int idx = it * 512 + t;
            int row = idx >> 5;
            int c4 = idx & 31;
            if (node0 + row < n) {
                float4 v = xg[(size_t)row * 32 + c4];
                float* dp = &xs[row * 132 + c4 * 4];
                dp[0] = v.x;
                dp[1] = v.y;
                dp[2] = v.z;
                dp[3] = v.w;
            }
        }
    }
    __syncthreads();
    const int node = node0 + (t >> 4);
    const int c = t & 15;
    if (node < n) {
        const float4* xr4 = (const float4*)&xs[(t >> 4) * 132];
        float acc = 0.f;
#pragma unroll
        for (int q = 0; q < 32; ++q) {
            float4 xv = xr4[q];
            acc += xv.x * Ws[(4 * q + 0) * 16 + c] +
                   xv.y * Ws[(4 * q + 1) * 16 + c] +
                   xv.z * Ws[(4 * q + 2) * 16 + c] +
                   xv.w * Ws[(4 * q + 3) * 16 + c];
        }
        hs[(size_t)node * 16 + c] = __float2half(dinv[node] * acc);
    }
}

__device__ __forceinline__ void unpack8(float4 r, float* f) {
    const __half2* hp = (const __half2*)&r;
#pragma unroll
    for (int q = 0; q < 4; ++q) {
        f[2 * q] = __low2float(hp[q]);
        f[2 * q + 1] = __high2float(hp[q]);
    }
}

// --- src-split gather. thread = (node, row-half). 8-edge unroll. ---------
template <bool L1, bool PASSB>
__global__ void k_gn(const int* __restrict__ rp2,
                     const int* __restrict__ bstart,
                     const int* __restrict__ adj,
                     const float* __restrict__ dinv,
                     const __half* __restrict__ hs,
                     const float* __restrict__ bias,
                     float* __restrict__ partial, void* __restrict__ o,
                     int n) {
    long long total = 2LL * n;
    long long i = (long long)blockIdx.x * blockDim.x + threadIdx.x;
    long long stride = (long long)gridDim.x * blockDim.x;
    for (; i < total; i += stride) {
        const int v = (int)(i >> 1);
        const int hf = (int)(i & 1);
        const int rowstart =
            ((v & (BUCKN - 1)) == 0) ? bstart[v >> BUCKSH] : rp2[2 * v - 1];
        const int s = PASSB ? rp2[2 * v] : rowstart;
        const int e = PASSB ? rp2[2 * v + 1] : rp2[2 * v];
        float acc[8];
        if (PASSB) {
            const float4* pp =
                (const float4*)(partial + (size_t)v * 16 + hf * 8);
            float4 a = pp[0], b = pp[1];
            acc[0] = a.x; acc[1] = a.y; acc[2] = a.z; acc[3] = a.w;
            acc[4] = b.x; acc[5] = b.y; acc[6] = b.z; acc[7] = b.w;
        } else {
#pragma unroll
            for (int q = 0; q < 8; ++q) acc[q] = 0.f;
        }
        int k = s;
        for (; k + 7 < e; k += 8) {
            int si[8];
#pragma unroll
            for (int q = 0; q < 8; ++q) si[q] = adj[k + q];
            float4 r[8];
#pragma unroll
            for (int q = 0; q < 8; ++q)
                r[q] = *(const float4*)(hs + (size_t)si[q] * 16 + hf * 8);
#pragma unroll
            for (int q = 0; q < 8; ++q) {
                float f[8];
                unpack8(r[q], f);
#pragma unroll
                for (int w = 0; w < 8; ++w) acc[w] += f[w];
            }
        }
        for (; k + 3 < e; k += 4) {
            int s0 = adj[k], s1 = adj[k + 1], s2 = adj[k + 2], s3 = adj[k + 3];
            float4 r0 = *(const float4*)(hs + (size_t)s0 * 16 + hf * 8);
            float4 r1 = *(const float4*)(hs + (size_t)s1 * 16 + hf * 8);
            float4 r2 = *(const float4*)(hs + (size_t)s2 * 16 + hf * 8);
            float4 r3 = *(const float4*)(hs + (size_t)s3 * 16 + hf * 8);
            float f0[8], f1[8], f2[8], f3[8];
            unpack8(r0, f0);
            unpack8(r1, f1);
            unpack8(r2, f2);
            unpack8(r3, f3);
#pragma unroll
            for (int q = 0; q < 8; ++q)
                acc[q] += (f0[q] + f1[q]) + (f2[q] + f3[q]);
        }
        for (; k < e; ++k) {
            float4 r = *(const float4*)(hs + (size_t)adj[k] * 16 + hf * 8);
            float f[8];
            unpack8(r, f);
#pragma unroll
            for (int q = 0; q < 8; ++q) acc[q] += f[q];
        }
        if (!PASSB) {
            float* pp = partial + (size_t)v * 16 + hf * 8;
            *(float4*)pp = make_float4(acc[0], acc[1], acc[2], acc[3]);
            *(float4*)(pp + 4) = make_float4(acc[4], acc[5], acc[6], acc[7]);
        } else {
            float4 rs = *(const float4*)(hs + (size_t)v * 16 + hf * 8);
            float fs[8];
            unpack8(rs, fs);
            const float dv = dinv[v];
            if (L1) {
                __half2 hr[4];
#pragma unroll
                for (int q = 0; q < 4; ++q) {
                    float v0 = dv * fmaxf(dv * (acc[2 * q] + fs[2 * q]) +
                                              bias[hf * 8 + 2 * q],
                                          0.f);
                    float v1 = dv * fmaxf(dv * (acc[2 * q + 1] + fs[2 * q + 1]) +
                                              bias[hf * 8 + 2 * q + 1],
                                          0.f);
                    hr[q] = __floats2half2_rn(v0, v1);
                }
                *(float4*)((__half*)o + (size_t)v * 16 + hf * 8) =
                    *(const float4*)hr;
            } else {
                float* op = (float*)o + (size_t)v * 16 + hf * 8;
                *(float4*)op =
                    make_float4(dv * (acc[0] + fs[0]), dv * (acc[1] + fs[1]),
                                dv * (acc[2] + fs[2]), dv * (acc[3] + fs[3]));
                *(float4*)(op + 4) =
                    make_float4(dv * (acc[4] + fs[4]), dv * (acc[5] + fs[5]),
                                dv * (acc[6] + fs[6]), dv * (acc[7] + fs[7]));
            }
        }
    }
}

// --- out = pre @ W2 + b2 --------------------------------------------------
__global__ void k_out(const float* __restrict__ pre,
                      const float* __restrict__ W2,
                      const float* __restrict__ b2, float* __restrict__ out,
                      int n) {
    __shared__ float Ws[16 * 32];
    for (int i = threadIdx.x; i < 16 * 32; i += blockDim.x) Ws[i] = W2[i];
    __syncthreads();
    long long total = (long long)n * 32;
    long long i = (long long)blockIdx.x * blockDim.x + threadIdx.x;
    long long stride = (long long)gridDim.x * blockDim.x;
    for (; i < total; i += stride) {
        int v = (int)(i >> 5);
        int c = (int)(i & 31);
        const float* pr = pre + (size_t)v * 16;
        float acc = b2[c];
#pragma unroll
        for (int j = 0; j < 16; ++j) acc += pr[j] * Ws[j * 32 + c];
        out[i] = acc;
    }
}

static inline int blocks_for(long long total) {
    return (int)((total + TPB - 1) / TPB);
}

extern "C" void kernel_launch(void* const* d_in, const int* in_sizes, int n_in,
                              void* d_out, int out_size, void* d_ws,
                              size_t ws_size, hipStream_t stream) {
    const float* x = (const float*)d_in[0];
    const int* ei = (const int*)d_in[1];
    const float* W1 = (const float*)d_in[2];
    const float* b1 = (const float*)d_in[3];
    const float* W2 = (const float*)d_in[4];
    const float* b2 = (const float*)d_in[5];
    float* out = (float*)d_out;

    const int n = in_sizes[0] / 128;  // 200000 nodes
    const int E = in_sizes[1] / 2;    // 6400000 edges
    const int* src = ei;
    const int* dst = ei + E;
    const int nbuck = (n + BUCKN - 1) / BUCKN;  // 196
    const int h = (n + 1) / 2;                  // src-half boundary

    char* ws = (char*)d_ws;
    float* dinv = (float*)ws;
    int* rp2 = (int*)(ws + (size_t)n * 4);
    int* adj = (int*)(ws + (size_t)n * 12);
    char* R = ws + (size_t)n * 12 + (size_t)E * 4;
    size_t base_bytes = (size_t)n * 12 + (size_t)E * 8;

    auto need = [&](int nbb) {
        return base_bytes +
               ((size_t)nbb + (size_t)nbb / SEGROWS + 2) * nbuck * 4 + 8192;
    };
    const int NBB =
        (ws_size >= need(2048)) ? 2048 : ((ws_size >= need(1024)) ? 1024 : 512);
    const int nseg = NBB / SEGROWS;
    const int chunk = (((E + NBB - 1) / NBB) + 3) & ~3;  // x4 for int4 loads

    int* hist = (int*)(R + (size_t)E * 4);
    int* segsum = hist + (size_t)NBB * nbuck;
    int* colsum = segsum + (size_t)nseg * nbuck;
    int* bstart = colsum + nbuck;
    int* bbuf = (int*)R;

    __half* h1s = (__half*)R;
    __half* z1s = (__half*)(R + (size_t)n * 32);
    float* pre = (float*)(R + (size_t)n * 64);

    const int cb = (nbuck + 255) / 256;  // 1

    // --- build ---
    k_hist<<<NBB, BINT, 0, stream>>>(dst, E, n, nbuck, chunk, hist);
    k_scanA1<<<dim3(cb, nseg), 256, 0, stream>>>(hist, nbuck, segsum);
    k_scanA2<<<cb, 256, 0, stream>>>(segsum, nbuck, nseg, colsum);
    k_scanB<<<1, 256, 0, stream>>>(colsum, nbuck, E, bstart);
    k_scanA3<<<dim3(cb, nseg), 256, 0, stream>>>(hist, nbuck, segsum);
    k_bin<<<NBB, BINT, 0, stream>>>(src, dst, E, n, nbuck, chunk, hist, bstart,
                                    bbuf);
    k_bucket2<<<nbuck, 1024, 0, stream>>>(bbuf, bstart, n, h, rp2, dinv, adj);

    // --- layer 1 ---
    k_mm1<<<(n + MMN - 1) / MMN, 512, 0, stream>>>(x, W1, dinv, n, h1s);
    k_gn<true, false><<<blocks_for(2LL * n), TPB, 0, stream>>>(
        rp2, bstart, adj, dinv, h1s, b1, pre, nullptr, n);
    k_gn<true, true><<<blocks_for(2LL * n), TPB, 0, stream>>>(
        rp2, bstart, adj, dinv, h1s, b1, pre, z1s, n);

    // --- layer 2 ---
    k_gn<false, false><<<blocks_for(2LL * n), TPB, 0, stream>>>(
        rp2, bstart, adj, dinv, z1s, nullptr, pre, nullptr, n);
    k_gn<false, true><<<blocks_for(2LL * n), TPB, 0, stream>>>(
        rp2, bstart, adj, dinv, z1s, nullptr, pre, pre, n);

    k_out<<<blocks_for((long long)n * 32), TPB, 0, stream>>>(pre, W2, b2, out,
                                                             n);
}

// Round 21
// 294.314 us; speedup vs baseline: 1.4939x; 1.0452x over previous
//
#include <hip/hip_runtime.h>
#include <hip/hip_fp16.h>

// ---------------------------------------------------------------------------
// 2-layer GCN, CSR with rows sub-sorted by source-half (src<h | src>=h).
// Binding constraint (r16): random-gather hot set must fit per-XCD L2
// (4 MB). Source-split passes: pass A walks A-edges (table rows [0,h) =
// 3.2 MB hot), pass B walks B-edges (rows [h,n)), accumulating onto pass-A
// partials. 2 passes x E/2 edges per layer.
//   build: k_hist -> scans -> k_bin (1024-node buckets, int4 edge reads)
//          k_bucket2: counting sort key=(dlow<<1)|srchalf, pass-split
//          scatter (4 key-range passes; fixed 9x write amp in r19)
//   L1: k_mm1 (h1s = dinv*(x@W1), fp16 n x 16) ; gnA -> partial(f32) ;
//       gnB -> z1s = dinv*relu(dinv*(agg+self)+b1) (fp16)
//   L2: gnA(z1s) -> partial ; gnB -> OUT DIRECTLY (k_out fused: thread
//       (v,hf) holds 8 final pre channels in regs; 8x32 FMA partial out,
//       __shfl_xor(.,1) combines the lane pair, lane hf writes 16 channels
//       + bias). Eliminates k_out's 51 MB of pre/out traffic + a launch.
// k_gn: thread = (node, row-half), 8-edge unroll. Grid covers 2n in one
// iteration so lane pairs (2v,2v+1) stay lockstep for the shuffle.
// Region R = bbuf then {h1s,z1s,partial}. Packing needs n < 2^18 (ok).
// ---------------------------------------------------------------------------

#define TPB 256
#define BINT 256
#define SEGROWS 64
#define BUCKSH 10
#define BUCKN (1 << BUCKSH)
#define MMN 32

__device__ __forceinline__ int clampi(int v, int n) {
    return v < 0 ? 0 : (v >= n ? n - 1 : v);
}

// --- per-block LDS histogram over contiguous edge range (int4 reads) -----
__global__ __launch_bounds__(BINT) void k_hist(const int* __restrict__ dst,
                                               int E, int n, int nbuck,
                                               int chunk,
                                               int* __restrict__ hist) {
    __shared__ int lh[256];
    const int b = blockIdx.x;
    const int t = threadIdx.x;
    lh[t] = 0;
    __syncthreads();
    const int start = b * chunk;
    const int end = min(E, start + chunk);
    for (int i = start + 4 * t; i < end; i += 4 * BINT) {
        if (i + 4 <= end) {
            int4 d4 = *(const int4*)(dst + i);
            atomicAdd(&lh[clampi(d4.x, n) >> BUCKSH], 1);
            atomicAdd(&lh[clampi(d4.y, n) >> BUCKSH], 1);
            atomicAdd(&lh[clampi(d4.z, n) >> BUCKSH], 1);
            atomicAdd(&lh[clampi(d4.w, n) >> BUCKSH], 1);
        } else {
            for (int j = i; j < end; ++j)
                atomicAdd(&lh[clampi(dst[j], n) >> BUCKSH], 1);
        }
    }
    __syncthreads();
    for (int k = t; k < nbuck; k += BINT) hist[b * nbuck + k] = lh[k];
}

// --- segmented column scan stage 1 ---------------------------------------
__global__ void k_scanA1(const int* __restrict__ hist, int nbuck,
                         int* __restrict__ segsum) {
    int k = blockIdx.x * blockDim.x + threadIdx.x;
    int seg = blockIdx.y;
    if (k >= nbuck) return;
    const int* row = hist + (size_t)seg * SEGROWS * nbuck + k;
    int sum = 0;
#pragma unroll
    for (int b = 0; b < SEGROWS; ++b) sum += row[(size_t)b * nbuck];
    segsum[seg * nbuck + k] = sum;
}

// --- stage 2 --------------------------------------------------------------
__global__ void k_scanA2(int* __restrict__ segsum, int nbuck, int nseg,
                         int* __restrict__ colsum) {
    int k = blockIdx.x * blockDim.x + threadIdx.x;
    if (k >= nbuck) return;
    int run = 0;
    for (int sg = 0; sg < nseg; ++sg) {
        int v = segsum[sg * nbuck + k];
        segsum[sg * nbuck + k] = run;
        run += v;
    }
    colsum[k] = run;
}

// --- exclusive scan of colsum -> bstart ----------------------------------
__global__ void k_scanB(const int* __restrict__ colsum, int nbuck, int E,
                        int* __restrict__ bstart) {
    __shared__ int s[256];
    const int t = threadIdx.x;
    int loc[4];
    int a = 0;
#pragma unroll
    for (int i = 0; i < 4; ++i) {
        int idx = 4 * t + i;
        loc[i] = (idx < nbuck) ? colsum[idx] : 0;
        a += loc[i];
    }
    s[t] = a;
    __syncthreads();
#pragma unroll
    for (int off = 1; off < 256; off <<= 1) {
        int v = (t >= off) ? s[t - off] : 0;
        __syncthreads();
        s[t] += v;
        __syncthreads();
    }
    int base = s[t] - a;
#pragma unroll
    for (int i = 0; i < 4; ++i) {
        int idx = 4 * t + i;
        if (idx < nbuck) bstart[idx] = base;
        base += loc[i];
    }
    if (t == 255) bstart[nbuck] = E;
}

// --- stage 3 --------------------------------------------------------------
__global__ void k_scanA3(int* __restrict__ hist, int nbuck,
                         const int* __restrict__ segsum) {
    int k = blockIdx.x * blockDim.x + threadIdx.x;
    int seg = blockIdx.y;
    if (k >= nbuck) return;
    int run = segsum[seg * nbuck + k];
    int* row = hist + (size_t)seg * SEGROWS * nbuck + k;
#pragma unroll
    for (int b = 0; b < SEGROWS; ++b) {
        int v = row[(size_t)b * nbuck];
        row[(size_t)b * nbuck] = run;
        run += v;
    }
}

// --- binning: LDS cursors; int4 edge reads, 4-way ILP --------------------
__global__ __launch_bounds__(BINT) void k_bin(const int* __restrict__ src,
                                              const int* __restrict__ dst,
                                              int E, int n, int nbuck,
                                              int chunk,
                                              const int* __restrict__ hist,
                                              const int* __restrict__ bstart,
                                              int* __restrict__ bbuf) {
    __shared__ int lcur[256];
    const int b = blockIdx.x;
    const int t = threadIdx.x;
    for (int k = t; k < nbuck; k += BINT)
        lcur[k] = bstart[k] + hist[b * nbuck + k];
    __syncthreads();
    const int start = b * chunk;
    const int end = min(E, start + chunk);
    for (int i = start + 4 * t; i < end; i += 4 * BINT) {
        if (i + 4 <= end) {
            int4 s4 = *(const int4*)(src + i);
            int4 d4 = *(const int4*)(dst + i);
            int s0 = clampi(s4.x, n), s1 = clampi(s4.y, n);
            int s2 = clampi(s4.z, n), s3 = clampi(s4.w, n);
            int d0 = clampi(d4.x, n), d1 = clampi(d4.y, n);
            int d2 = clampi(d4.z, n), d3 = clampi(d4.w, n);
            int p0 = atomicAdd(&lcur[d0 >> BUCKSH], 1);
            int p1 = atomicAdd(&lcur[d1 >> BUCKSH], 1);
            int p2 = atomicAdd(&lcur[d2 >> BUCKSH], 1);
            int p3 = atomicAdd(&lcur[d3 >> BUCKSH], 1);
            bbuf[p0] = ((d0 & (BUCKN - 1)) << 18) | s0;
            bbuf[p1] = ((d1 & (BUCKN - 1)) << 18) | s1;
            bbuf[p2] = ((d2 & (BUCKN - 1)) << 18) | s2;
            bbuf[p3] = ((d3 & (BUCKN - 1)) << 18) | s3;
        } else {
            for (int j = i; j < end; ++j) {
                int s0 = clampi(src[j], n);
                int d0 = clampi(dst[j], n);
                int p0 = atomicAdd(&lcur[d0 >> BUCKSH], 1);
                bbuf[p0] = ((d0 & (BUCKN - 1)) << 18) | s0;
            }
        }
    }
}

// --- per-bucket counting sort, key=(dlow<<1)|srchalf; PASS-SPLIT scatter -
__global__ __launch_bounds__(1024) void k_bucket2(
    const int* __restrict__ bbuf, const int* __restrict__ bstart, int n, int h,
    int* __restrict__ rp2, float* __restrict__ dinv, int* __restrict__ adj) {
    __shared__ int lcnt[2048];
    __shared__ int wsum[16];
    const int b = blockIdx.x;
    const int t = threadIdx.x;
    const int start = bstart[b];
    const int end = bstart[b + 1];

    lcnt[t] = 0;
    lcnt[t + 1024] = 0;
    __syncthreads();
    {
        int i = start + t;
        for (; i + 7 * 1024 < end; i += 8 * 1024) {
            int p[8], k[8];
#pragma unroll
            for (int q = 0; q < 8; ++q) p[q] = bbuf[i + q * 1024];
#pragma unroll
            for (int q = 0; q < 8; ++q)
                k[q] = ((((unsigned)p[q]) >> 18) << 1) |
                       ((p[q] & 0x3FFFF) >= h);
#pragma unroll
            for (int q = 0; q < 8; ++q) atomicAdd(&lcnt[k[q]], 1);
        }
        for (; i < end; i += 1024) {
            int p = bbuf[i];
            int k = ((((unsigned)p) >> 18) << 1) | ((p & 0x3FFFF) >= h);
            atomicAdd(&lcnt[k], 1);
        }
    }
    __syncthreads();

    const int c0 = lcnt[2 * t];
    const int c1 = lcnt[2 * t + 1];
    const int psum = c0 + c1;
    int val = psum;
#pragma unroll
    for (int off = 1; off < 64; off <<= 1) {
        int vv = __shfl_up(val, off, 64);
        if ((t & 63) >= off) val += vv;
    }
    if ((t & 63) == 63) wsum[t >> 6] = val;
    __syncthreads();
    if (t == 0) {
        int run = 0;
#pragma unroll
        for (int w = 0; w < 16; ++w) {
            int v = wsum[w];
            wsum[w] = run;
            run += v;
        }
    }
    __syncthreads();
    const int exclPair = val + wsum[t >> 6] - psum;
    const int v = (b << BUCKSH) + t;
    if (v < n) {
        rp2[2 * v] = start + exclPair + c0;
        rp2[2 * v + 1] = start + exclPair + c0 + c1;
        dinv[v] = rsqrtf((float)(c0 + c1 + 1));
    }
    lcnt[2 * t] = start + exclPair;
    lcnt[2 * t + 1] = start + exclPair + c0;
    __syncthreads();

    // 4 key-range passes keep the active write window at 512 lines/block.
#pragma unroll 1
    for (int p4 = 0; p4 < 4; ++p4) {
        const int keylo = p4 << 9;
        const int keyhi = keylo + 512;
        int i = start + t;
        for (; i + 3 * 1024 < end; i += 4 * 1024) {
            int p[4], k[4];
#pragma unroll
            for (int q = 0; q < 4; ++q) p[q] = bbuf[i + q * 1024];
#pragma unroll
            for (int q = 0; q < 4; ++q)
                k[q] = ((((unsigned)p[q]) >> 18) << 1) |
                       ((p[q] & 0x3FFFF) >= h);
#pragma unroll
            for (int q = 0; q < 4; ++q) {
                if (k[q] >= keylo && k[q] < keyhi) {
                    int pos = atomicAdd(&lcnt[k[q]], 1);
                    adj[pos] = p[q] & 0x3FFFF;
                }
            }
        }
        for (; i < end; i += 1024) {
            int p = bbuf[i];
            int k = ((((unsigned)p) >> 18) << 1) | ((p & 0x3FFFF) >= h);
            if (k >= keylo && k < keyhi) {
                int pos = atomicAdd(&lcnt[k], 1);
                adj[pos] = p & 0x3FFFF;
            }
        }
        __syncthreads();
    }
}

// --- h1s = dinv*(x@W1): LDS-staged tile, 16-ch fp16 table ----------------
__global__ __launch_bounds__(512) void k_mm1(const float* __restrict__ x,
                                             const float* __restrict__ W,
                                             const float* __restrict__ dinv,
                                             int n, __half* __restrict__ hs) {
    __shared__ float Ws[128 * 16];
    __shared__ float xs[MMN * 132];
    const int t = threadIdx.x;
    for (int i = t; i < 128 * 16; i += 512) Ws[i] = W[i];
    const int node0 = blockIdx.x * MMN;
    {
        const float4* xg = (const float4*)(x + (size_t)node0 * 128);
#pragma unroll
        for (int it = 0; it < 2; ++it) {
            int idx = it * 512 + t;
            int row = idx >> 5;
            int c4 = idx & 31;
            if (node0 + row < n) {
                float4 v = xg[(size_t)row * 32 + c4];
                float* dp = &xs[row * 132 + c4 * 4];
                dp[0] = v.x;
                dp[1] = v.y;
                dp[2] = v.z;
                dp[3] = v.w;
            }
        }
    }
    __syncthreads();
    const int node = node0 + (t >> 4);
    const int c = t & 15;
    if (node < n) {
        const float4* xr4 = (const float4*)&xs[(t >> 4) * 132];
        float acc = 0.f;
#pragma unroll
        for (int q = 0; q < 32; ++q) {
            float4 xv = xr4[q];
            acc += xv.x * Ws[(4 * q + 0) * 16 + c] +
                   xv.y * Ws[(4 * q + 1) * 16 + c] +
                   xv.z * Ws[(4 * q + 2) * 16 + c] +
                   xv.w * Ws[(4 * q + 3) * 16 + c];
        }
        hs[(size_t)node * 16 + c] = __float2half(dinv[node] * acc);
    }
}

__device__ __forceinline__ void unpack8(float4 r, float* f) {
    const __half2* hp = (const __half2*)&r;
#pragma unroll
    for (int q = 0; q < 4; ++q) {
        f[2 * q] = __low2float(hp[q]);
        f[2 * q + 1] = __high2float(hp[q]);
    }
}

// --- src-split gather. thread = (node, row-half). 8-edge unroll. ---------
// PASSA: acc=0, walk A-range -> store f32 partial.
// PASSB+L1: acc=partial, walk B-range, self, relu -> fp16 z1s.
// PASSB+L2 (FUSE): finalize pre in regs, compute 8x32 partial out, combine
// lane pair via __shfl_xor(.,1), lane hf writes out channels [16hf,16hf+16).
template <bool L1, bool PASSB>
__global__ void k_gn(const int* __restrict__ rp2,
                     const int* __restrict__ bstart,
                     const int* __restrict__ adj,
                     const float* __restrict__ dinv,
                     const __half* __restrict__ hs,
                     const float* __restrict__ bias,
                     const float* __restrict__ W2,
                     float* __restrict__ partial, void* __restrict__ o,
                     int n) {
    constexpr bool FUSE = (!L1 && PASSB);
    __shared__ float W2s[16 * 32];
    if (FUSE) {
        for (int i = threadIdx.x; i < 16 * 32; i += blockDim.x)
            W2s[i] = W2[i];
        __syncthreads();
    }
    long long total = 2LL * n;
    long long i = (long long)blockIdx.x * blockDim.x + threadIdx.x;
    long long stride = (long long)gridDim.x * blockDim.x;
    for (; i < total; i += stride) {
        const int v = (int)(i >> 1);
        const int hf = (int)(i & 1);
        const int rowstart =
            ((v & (BUCKN - 1)) == 0) ? bstart[v >> BUCKSH] : rp2[2 * v - 1];
        const int s = PASSB ? rp2[2 * v] : rowstart;
        const int e = PASSB ? rp2[2 * v + 1] : rp2[2 * v];
        float acc[8];
        if (PASSB) {
            const float4* pp =
                (const float4*)(partial + (size_t)v * 16 + hf * 8);
            float4 a = pp[0], b = pp[1];
            acc[0] = a.x; acc[1] = a.y; acc[2] = a.z; acc[3] = a.w;
            acc[4] = b.x; acc[5] = b.y; acc[6] = b.z; acc[7] = b.w;
        } else {
#pragma unroll
            for (int q = 0; q < 8; ++q) acc[q] = 0.f;
        }
        int k = s;
        for (; k + 7 < e; k += 8) {
            int si[8];
#pragma unroll
            for (int q = 0; q < 8; ++q) si[q] = adj[k + q];
            float4 r[8];
#pragma unroll
            for (int q = 0; q < 8; ++q)
                r[q] = *(const float4*)(hs + (size_t)si[q] * 16 + hf * 8);
#pragma unroll
            for (int q = 0; q < 8; ++q) {
                float f[8];
                unpack8(r[q], f);
#pragma unroll
                for (int w = 0; w < 8; ++w) acc[w] += f[w];
            }
        }
        for (; k + 3 < e; k += 4) {
            int s0 = adj[k], s1 = adj[k + 1], s2 = adj[k + 2], s3 = adj[k + 3];
            float4 r0 = *(const float4*)(hs + (size_t)s0 * 16 + hf * 8);
            float4 r1 = *(const float4*)(hs + (size_t)s1 * 16 + hf * 8);
            float4 r2 = *(const float4*)(hs + (size_t)s2 * 16 + hf * 8);
            float4 r3 = *(const float4*)(hs + (size_t)s3 * 16 + hf * 8);
            float f0[8], f1[8], f2[8], f3[8];
            unpack8(r0, f0);
            unpack8(r1, f1);
            unpack8(r2, f2);
            unpack8(r3, f3);
#pragma unroll
            for (int q = 0; q < 8; ++q)
                acc[q] += (f0[q] + f1[q]) + (f2[q] + f3[q]);
        }
        for (; k < e; ++k) {
            float4 r = *(const float4*)(hs + (size_t)adj[k] * 16 + hf * 8);
            float f[8];
            unpack8(r, f);
#pragma unroll
            for (int q = 0; q < 8; ++q) acc[q] += f[q];
        }
        if (!PASSB) {
            float* pp = partial + (size_t)v * 16 + hf * 8;
            *(float4*)pp = make_float4(acc[0], acc[1], acc[2], acc[3]);
            *(float4*)(pp + 4) = make_float4(acc[4], acc[5], acc[6], acc[7]);
        } else {
            float4 rs = *(const float4*)(hs + (size_t)v * 16 + hf * 8);
            float fs[8];
            unpack8(rs, fs);
            const float dv = dinv[v];
            if (L1) {
                __half2 hr[4];
#pragma unroll
                for (int q = 0; q < 4; ++q) {
                    float v0 = dv * fmaxf(dv * (acc[2 * q] + fs[2 * q]) +
                                              bias[hf * 8 + 2 * q],
                                          0.f);
                    float v1 = dv * fmaxf(dv * (acc[2 * q + 1] + fs[2 * q + 1]) +
                                              bias[hf * 8 + 2 * q + 1],
                                          0.f);
                    hr[q] = __floats2half2_rn(v0, v1);
                }
                *(float4*)((__half*)o + (size_t)v * 16 + hf * 8) =
                    *(const float4*)hr;
            } else {
                // FUSE: pre -> out = pre @ W2 + b2, lane-pair combine
                float prev[8];
#pragma unroll
                for (int q = 0; q < 8; ++q)
                    prev[q] = dv * (acc[q] + fs[q]);
                float po[32];
#pragma unroll
                for (int c = 0; c < 32; ++c) po[c] = 0.f;
#pragma unroll
                for (int j = 0; j < 8; ++j) {
                    const float* wrow = &W2s[(hf * 8 + j) * 32];
#pragma unroll
                    for (int c = 0; c < 32; ++c) po[c] += prev[j] * wrow[c];
                }
#pragma unroll
                for (int c = 0; c < 32; ++c)
                    po[c] += __shfl_xor(po[c], 1, 64);
                float* op = (float*)o + (size_t)v * 32 + hf * 16;
#pragma unroll
                for (int g = 0; g < 4; ++g) {
                    int c0 = hf * 16 + 4 * g;
                    *(float4*)(op + 4 * g) = make_float4(
                        po[c0] + bias[c0], po[c0 + 1] + bias[c0 + 1],
                        po[c0 + 2] + bias[c0 + 2], po[c0 + 3] + bias[c0 + 3]);
                }
            }
        }
    }
}

static inline int blocks_for(long long total) {
    return (int)((total + TPB - 1) / TPB);
}

extern "C" void kernel_launch(void* const* d_in, const int* in_sizes, int n_in,
                              void* d_out, int out_size, void* d_ws,
                              size_t ws_size, hipStream_t stream) {
    const float* x = (const float*)d_in[0];
    const int* ei = (const int*)d_in[1];
    const float* W1 = (const float*)d_in[2];
    const float* b1 = (const float*)d_in[3];
    const float* W2 = (const float*)d_in[4];
    const float* b2 = (const float*)d_in[5];
    float* out = (float*)d_out;

    const int n = in_sizes[0] / 128;  // 200000 nodes
    const int E = in_sizes[1] / 2;    // 6400000 edges
    const int* src = ei;
    const int* dst = ei + E;
    const int nbuck = (n + BUCKN - 1) / BUCKN;  // 196
    const int h = (n + 1) / 2;                  // src-half boundary

    char* ws = (char*)d_ws;
    float* dinv = (float*)ws;
    int* rp2 = (int*)(ws + (size_t)n * 4);
    int* adj = (int*)(ws + (size_t)n * 12);
    char* R = ws + (size_t)n * 12 + (size_t)E * 4;
    size_t base_bytes = (size_t)n * 12 + (size_t)E * 8;

    auto need = [&](int nbb) {
        return base_bytes +
               ((size_t)nbb + (size_t)nbb / SEGROWS + 2) * nbuck * 4 + 8192;
    };
    const int NBB =
        (ws_size >= need(2048)) ? 2048 : ((ws_size >= need(1024)) ? 1024 : 512);
    const int nseg = NBB / SEGROWS;
    const int chunk = (((E + NBB - 1) / NBB) + 3) & ~3;  // x4 for int4 loads

    int* hist = (int*)(R + (size_t)E * 4);
    int* segsum = hist + (size_t)NBB * nbuck;
    int* colsum = segsum + (size_t)nseg * nbuck;
    int* bstart = colsum + nbuck;
    int* bbuf = (int*)R;

    __half* h1s = (__half*)R;
    __half* z1s = (__half*)(R + (size_t)n * 32);
    float* partial = (float*)(R + (size_t)n * 64);

    const int cb = (nbuck + 255) / 256;  // 1

    // --- build ---
    k_hist<<<NBB, BINT, 0, stream>>>(dst, E, n, nbuck, chunk, hist);
    k_scanA1<<<dim3(cb, nseg), 256, 0, stream>>>(hist, nbuck, segsum);
    k_scanA2<<<cb, 256, 0, stream>>>(segsum, nbuck, nseg, colsum);
    k_scanB<<<1, 256, 0, stream>>>(colsum, nbuck, E, bstart);
    k_scanA3<<<dim3(cb, nseg), 256, 0, stream>>>(hist, nbuck, segsum);
    k_bin<<<NBB, BINT, 0, stream>>>(src, dst, E, n, nbuck, chunk, hist, bstart,
                                    bbuf);
    k_bucket2<<<nbuck, 1024, 0, stream>>>(bbuf, bstart, n, h, rp2, dinv, adj);

    // --- layer 1 ---
    k_mm1<<<(n + MMN - 1) / MMN, 512, 0, stream>>>(x, W1, dinv, n, h1s);
    k_gn<true, false><<<blocks_for(2LL * n), TPB, 0, stream>>>(
        rp2, bstart, adj, dinv, h1s, b1, nullptr, partial, nullptr, n);
    k_gn<true, true><<<blocks_for(2LL * n), TPB, 0, stream>>>(
        rp2, bstart, adj, dinv, h1s, b1, nullptr, partial, z1s, n);

    // --- layer 2 (k_out fused into gnB) ---
    k_gn<false, false><<<blocks_for(2LL * n), TPB, 0, stream>>>(
        rp2, bstart, adj, dinv, z1s, nullptr, nullptr, partial, nullptr, n);
    k_gn<false, true><<<blocks_for(2LL * n), TPB, 0, stream>>>(
        rp2, bstart, adj, dinv, z1s, b2, W2, partial, out, n);
}

// Round 22
// 262.190 us; speedup vs baseline: 1.6770x; 1.1225x over previous
//
#include <hip/hip_runtime.h>
#include <hip/hip_fp16.h>

// ---------------------------------------------------------------------------
// 2-layer GCN, CSR with rows sub-sorted by source-half (src<h | src>=h).
// Binding constraint (r16): random-gather hot set must fit per-XCD L2
// (4 MB). Source-split passes: pass A walks A-edges (table rows [0,h) =
// 3.2 MB hot), pass B walks B-edges (rows [h,n)), accumulating onto pass-A
// partials. 2 passes x E/2 edges per layer.
//   build: k_hist -> scans -> k_bin (1024-node buckets, int4 edge reads)
//          k_bucket2: counting sort key=(dlow<<1)|srchalf with LDS-STAGED
//          scatter: dest[pos-start] in 140 KB LDS, then streamed to adj
//          coalesced. bbuf read 2x (was 5x with r19's pass-split) and adj
//          written full-line. Fallback to direct global scatter if a bucket
//          ever exceeds CAP (mean 32768, CAP=35840 = +17 sigma).
//   L1: k_mm1 (h1s = dinv*(x@W1), fp16 n x 16) ; gnA -> partial(f32) ;
//       gnB -> z1s = dinv*relu(dinv*(agg+self)+b1) (fp16)
//   L2: gnA(z1s) -> partial ; gnB -> OUT DIRECTLY (k_out fused via
//       __shfl_xor lane-pair combine; r21: -14 us)
// k_gn: thread = (node, row-half), 8-edge unroll.
// Region R = bbuf then {h1s,z1s,partial}. Packing needs n < 2^18 (ok).
// ---------------------------------------------------------------------------

#define TPB 256
#define BINT 256
#define SEGROWS 64
#define BUCKSH 10
#define BUCKN (1 << BUCKSH)
#define MMN 32
#define CAP 35840   // LDS staging capacity (ints) for one bucket's edges

__device__ __forceinline__ int clampi(int v, int n) {
    return v < 0 ? 0 : (v >= n ? n - 1 : v);
}

// --- per-block LDS histogram over contiguous edge range (int4 reads) -----
__global__ __launch_bounds__(BINT) void k_hist(const int* __restrict__ dst,
                                               int E, int n, int nbuck,
                                               int chunk,
                                               int* __restrict__ hist) {
    __shared__ int lh[256];
    const int b = blockIdx.x;
    const int t = threadIdx.x;
    lh[t] = 0;
    __syncthreads();
    const int start = b * chunk;
    const int end = min(E, start + chunk);
    for (int i = start + 4 * t; i < end; i += 4 * BINT) {
        if (i + 4 <= end) {
            int4 d4 = *(const int4*)(dst + i);
            atomicAdd(&lh[clampi(d4.x, n) >> BUCKSH], 1);
            atomicAdd(&lh[clampi(d4.y, n) >> BUCKSH], 1);
            atomicAdd(&lh[clampi(d4.z, n) >> BUCKSH], 1);
            atomicAdd(&lh[clampi(d4.w, n) >> BUCKSH], 1);
        } else {
            for (int j = i; j < end; ++j)
                atomicAdd(&lh[clampi(dst[j], n) >> BUCKSH], 1);
        }
    }
    __syncthreads();
    for (int k = t; k < nbuck; k += BINT) hist[b * nbuck + k] = lh[k];
}

// --- segmented column scan stage 1 ---------------------------------------
__global__ void k_scanA1(const int* __restrict__ hist, int nbuck,
                         int* __restrict__ segsum) {
    int k = blockIdx.x * blockDim.x + threadIdx.x;
    int seg = blockIdx.y;
    if (k >= nbuck) return;
    const int* row = hist + (size_t)seg * SEGROWS * nbuck + k;
    int sum = 0;
#pragma unroll
    for (int b = 0; b < SEGROWS; ++b) sum += row[(size_t)b * nbuck];
    segsum[seg * nbuck + k] = sum;
}

// --- stage 2 --------------------------------------------------------------
__global__ void k_scanA2(int* __restrict__ segsum, int nbuck, int nseg,
                         int* __restrict__ colsum) {
    int k = blockIdx.x * blockDim.x + threadIdx.x;
    if (k >= nbuck) return;
    int run = 0;
    for (int sg = 0; sg < nseg; ++sg) {
        int v = segsum[sg * nbuck + k];
        segsum[sg * nbuck + k] = run;
        run += v;
    }
    colsum[k] = run;
}

// --- exclusive scan of colsum -> bstart ----------------------------------
__global__ void k_scanB(const int* __restrict__ colsum, int nbuck, int E,
                        int* __restrict__ bstart) {
    __shared__ int s[256];
    const int t = threadIdx.x;
    int loc[4];
    int a = 0;
#pragma unroll
    for (int i = 0; i < 4; ++i) {
        int idx = 4 * t + i;
        loc[i] = (idx < nbuck) ? colsum[idx] : 0;
        a += loc[i];
    }
    s[t] = a;
    __syncthreads();
#pragma unroll
    for (int off = 1; off < 256; off <<= 1) {
        int v = (t >= off) ? s[t - off] : 0;
        __syncthreads();
        s[t] += v;
        __syncthreads();
    }
    int base = s[t] - a;
#pragma unroll
    for (int i = 0; i < 4; ++i) {
        int idx = 4 * t + i;
        if (idx < nbuck) bstart[idx] = base;
        base += loc[i];
    }
    if (t == 255) bstart[nbuck] = E;
}

// --- stage 3 --------------------------------------------------------------
__global__ void k_scanA3(int* __restrict__ hist, int nbuck,
                         const int* __restrict__ segsum) {
    int k = blockIdx.x * blockDim.x + threadIdx.x;
    int seg = blockIdx.y;
    if (k >= nbuck) return;
    int run = segsum[seg * nbuck + k];
    int* row = hist + (size_t)seg * SEGROWS * nbuck + k;
#pragma unroll
    for (int b = 0; b < SEGROWS; ++b) {
        int v = row[(size_t)b * nbuck];
        row[(size_t)b * nbuck] = run;
        run += v;
    }
}

// --- binning: LDS cursors; int4 edge reads, 4-way ILP --------------------
__global__ __launch_bounds__(BINT) void k_bin(const int* __restrict__ src,
                                              const int* __restrict__ dst,
                                              int E, int n, int nbuck,
                                              int chunk,
                                              const int* __restrict__ hist,
                                              const int* __restrict__ bstart,
                                              int* __restrict__ bbuf) {
    __shared__ int lcur[256];
    const int b = blockIdx.x;
    const int t = threadIdx.x;
    for (int k = t; k < nbuck; k += BINT)
        lcur[k] = bstart[k] + hist[b * nbuck + k];
    __syncthreads();
    const int start = b * chunk;
    const int end = min(E, start + chunk);
    for (int i = start + 4 * t; i < end; i += 4 * BINT) {
        if (i + 4 <= end) {
            int4 s4 = *(const int4*)(src + i);
            int4 d4 = *(const int4*)(dst + i);
            int s0 = clampi(s4.x, n), s1 = clampi(s4.y, n);
            int s2 = clampi(s4.z, n), s3 = clampi(s4.w, n);
            int d0 = clampi(d4.x, n), d1 = clampi(d4.y, n);
            int d2 = clampi(d4.z, n), d3 = clampi(d4.w, n);
            int p0 = atomicAdd(&lcur[d0 >> BUCKSH], 1);
            int p1 = atomicAdd(&lcur[d1 >> BUCKSH], 1);
            int p2 = atomicAdd(&lcur[d2 >> BUCKSH], 1);
            int p3 = atomicAdd(&lcur[d3 >> BUCKSH], 1);
            bbuf[p0] = ((d0 & (BUCKN - 1)) << 18) | s0;
            bbuf[p1] = ((d1 & (BUCKN - 1)) << 18) | s1;
            bbuf[p2] = ((d2 & (BUCKN - 1)) << 18) | s2;
            bbuf[p3] = ((d3 & (BUCKN - 1)) << 18) | s3;
        } else {
            for (int j = i; j < end; ++j) {
                int s0 = clampi(src[j], n);
                int d0 = clampi(dst[j], n);
                int p0 = atomicAdd(&lcur[d0 >> BUCKSH], 1);
                bbuf[p0] = ((d0 & (BUCKN - 1)) << 18) | s0;
            }
        }
    }
}

// --- per-bucket counting sort; LDS-STAGED scatter ------------------------
__global__ __launch_bounds__(1024) void k_bucket2(
    const int* __restrict__ bbuf, const int* __restrict__ bstart, int n, int h,
    int* __restrict__ rp2, float* __restrict__ dinv, int* __restrict__ adj) {
    __shared__ int lcnt[2048];
    __shared__ int wsum[16];
    __shared__ int dest[CAP];
    const int b = blockIdx.x;
    const int t = threadIdx.x;
    const int start = bstart[b];
    const int end = bstart[b + 1];
    const int cnt = end - start;

    lcnt[t] = 0;
    lcnt[t + 1024] = 0;
    __syncthreads();
    {
        int i = start + t;
        for (; i + 7 * 1024 < end; i += 8 * 1024) {
            int p[8], k[8];
#pragma unroll
            for (int q = 0; q < 8; ++q) p[q] = bbuf[i + q * 1024];
#pragma unroll
            for (int q = 0; q < 8; ++q)
                k[q] = ((((unsigned)p[q]) >> 18) << 1) |
                       ((p[q] & 0x3FFFF) >= h);
#pragma unroll
            for (int q = 0; q < 8; ++q) atomicAdd(&lcnt[k[q]], 1);
        }
        for (; i < end; i += 1024) {
            int p = bbuf[i];
            int k = ((((unsigned)p) >> 18) << 1) | ((p & 0x3FFFF) >= h);
            atomicAdd(&lcnt[k], 1);
        }
    }
    __syncthreads();

    const int c0 = lcnt[2 * t];
    const int c1 = lcnt[2 * t + 1];
    const int psum = c0 + c1;
    int val = psum;
#pragma unroll
    for (int off = 1; off < 64; off <<= 1) {
        int vv = __shfl_up(val, off, 64);
        if ((t & 63) >= off) val += vv;
    }
    if ((t & 63) == 63) wsum[t >> 6] = val;
    __syncthreads();
    if (t == 0) {
        int run = 0;
#pragma unroll
        for (int w = 0; w < 16; ++w) {
            int v = wsum[w];
            wsum[w] = run;
            run += v;
        }
    }
    __syncthreads();
    const int exclPair = val + wsum[t >> 6] - psum;
    const int v = (b << BUCKSH) + t;
    if (v < n) {
        rp2[2 * v] = start + exclPair + c0;
        rp2[2 * v + 1] = start + exclPair + c0 + c1;
        dinv[v] = rsqrtf((float)(c0 + c1 + 1));
    }
    lcnt[2 * t] = start + exclPair;
    lcnt[2 * t + 1] = start + exclPair + c0;
    __syncthreads();

    if (cnt <= CAP) {
        // scatter into LDS (dest index = pos - start), then stream out.
        int i = start + t;
        for (; i + 3 * 1024 < end; i += 4 * 1024) {
            int p[4], k[4], q4[4];
#pragma unroll
            for (int q = 0; q < 4; ++q) p[q] = bbuf[i + q * 1024];
#pragma unroll
            for (int q = 0; q < 4; ++q)
                k[q] = ((((unsigned)p[q]) >> 18) << 1) |
                       ((p[q] & 0x3FFFF) >= h);
#pragma unroll
            for (int q = 0; q < 4; ++q) q4[q] = atomicAdd(&lcnt[k[q]], 1);
#pragma unroll
            for (int q = 0; q < 4; ++q) dest[q4[q] - start] = p[q] & 0x3FFFF;
        }
        for (; i < end; i += 1024) {
            int p = bbuf[i];
            int k = ((((unsigned)p) >> 18) << 1) | ((p & 0x3FFFF) >= h);
            int pos = atomicAdd(&lcnt[k], 1);
            dest[pos - start] = p & 0x3FFFF;
        }
        __syncthreads();
        for (int j = t; j < cnt; j += 1024) adj[start + j] = dest[j];
    } else {
        // statistically unreachable fallback: direct global scatter
        int i = start + t;
        for (; i < end; i += 1024) {
            int p = bbuf[i];
            int k = ((((unsigned)p) >> 18) << 1) | ((p & 0x3FFFF) >= h);
            int pos = atomicAdd(&lcnt[k], 1);
            adj[pos] = p & 0x3FFFF;
        }
    }
}

// --- h1s = dinv*(x@W1): LDS-staged tile, 16-ch fp16 table ----------------
__global__ __launch_bounds__(512) void k_mm1(const float* __restrict__ x,
                                             const float* __restrict__ W,
                                             const float* __restrict__ dinv,
                                             int n, __half* __restrict__ hs) {
    __shared__ float Ws[128 * 16];
    __shared__ float xs[MMN * 132];
    const int t = threadIdx.x;
    for (int i = t; i < 128 * 16; i += 512) Ws[i] = W[i];
    const int node0 = blockIdx.x * MMN;
    {
        const float4* xg = (const float4*)(x + (size_t)node0 * 128);
#pragma unroll
        for (int it = 0; it < 2; ++it) {
            int idx = it * 512 + t;
            int row = idx >> 5;
            int c4 = idx & 31;
            if (node0 + row < n) {
                float4 v = xg[(size_t)row * 32 + c4];
                float* dp = &xs[row * 132 + c4 * 4];
                dp[0] = v.x;
                dp[1] = v.y;
                dp[2] = v.z;
                dp[3] = v.w;
            }
        }
    }
    __syncthreads();
    const int node = node0 + (t >> 4);
    const int c = t & 15;
    if (node < n) {
        const float4* xr4 = (const float4*)&xs[(t >> 4) * 132];
        float acc = 0.f;
#pragma unroll
        for (int q = 0; q < 32; ++q) {
            float4 xv = xr4[q];
            acc += xv.x * Ws[(4 * q + 0) * 16 + c] +
                   xv.y * Ws[(4 * q + 1) * 16 + c] +
                   xv.z * Ws[(4 * q + 2) * 16 + c] +
                   xv.w * Ws[(4 * q + 3) * 16 + c];
        }
        hs[(size_t)node * 16 + c] = __float2half(dinv[node] * acc);
    }
}

__device__ __forceinline__ void unpack8(float4 r, float* f) {
    const __half2* hp = (const __half2*)&r;
#pragma unroll
    for (int q = 0; q < 4; ++q) {
        f[2 * q] = __low2float(hp[q]);
        f[2 * q + 1] = __high2float(hp[q]);
    }
}

// --- src-split gather. thread = (node, row-half). 8-edge unroll. ---------
// PASSA: acc=0, walk A-range -> store f32 partial.
// PASSB+L1: acc=partial, walk B-range, self, relu -> fp16 z1s.
// PASSB+L2 (FUSE): finalize pre in regs, 8x32 partial out, __shfl_xor(.,1)
// lane-pair combine, lane hf writes out channels [16hf,16hf+16) + bias.
template <bool L1, bool PASSB>
__global__ void k_gn(const int* __restrict__ rp2,
                     const int* __restrict__ bstart,
                     const int* __restrict__ adj,
                     const float* __restrict__ dinv,
                     const __half* __restrict__ hs,
                     const float* __restrict__ bias,
                     const float* __restrict__ W2,
                     float* __restrict__ partial, void* __restrict__ o,
                     int n) {
    constexpr bool FUSE = (!L1 && PASSB);
    __shared__ float W2s[16 * 32];
    if (FUSE) {
        for (int i = threadIdx.x; i < 16 * 32; i += blockDim.x)
            W2s[i] = W2[i];
        __syncthreads();
    }
    long long total = 2LL * n;
    long long i = (long long)blockIdx.x * blockDim.x + threadIdx.x;
    long long stride = (long long)gridDim.x * blockDim.x;
    for (; i < total; i += stride) {
        const int v = (int)(i >> 1);
        const int hf = (int)(i & 1);
        const int rowstart =
            ((v & (BUCKN - 1)) == 0) ? bstart[v >> BUCKSH] : rp2[2 * v - 1];
        const int s = PASSB ? rp2[2 * v] : rowstart;
        const int e = PASSB ? rp2[2 * v + 1] : rp2[2 * v];
        float acc[8];
        if (PASSB) {
            const float4* pp =
                (const float4*)(partial + (size_t)v * 16 + hf * 8);
            float4 a = pp[0], b = pp[1];
            acc[0] = a.x; acc[1] = a.y; acc[2] = a.z; acc[3] = a.w;
            acc[4] = b.x; acc[5] = b.y; acc[6] = b.z; acc[7] = b.w;
        } else {
#pragma unroll
            for (int q = 0; q < 8; ++q) acc[q] = 0.f;
        }
        int k = s;
        for (; k + 7 < e; k += 8) {
            int si[8];
#pragma unroll
            for (int q = 0; q < 8; ++q) si[q] = adj[k + q];
            float4 r[8];
#pragma unroll
            for (int q = 0; q < 8; ++q)
                r[q] = *(const float4*)(hs + (size_t)si[q] * 16 + hf * 8);
#pragma unroll
            for (int q = 0; q < 8; ++q) {
                float f[8];
                unpack8(r[q], f);
#pragma unroll
                for (int w = 0; w < 8; ++w) acc[w] += f[w];
            }
        }
        for (; k + 3 < e; k += 4) {
            int s0 = adj[k], s1 = adj[k + 1], s2 = adj[k + 2], s3 = adj[k + 3];
            float4 r0 = *(const float4*)(hs + (size_t)s0 * 16 + hf * 8);
            float4 r1 = *(const float4*)(hs + (size_t)s1 * 16 + hf * 8);
            float4 r2 = *(const float4*)(hs + (size_t)s2 * 16 + hf * 8);
            float4 r3 = *(const float4*)(hs + (size_t)s3 * 16 + hf * 8);
            float f0[8], f1[8], f2[8], f3[8];
            unpack8(r0, f0);
            unpack8(r1, f1);
            unpack8(r2, f2);
            unpack8(r3, f3);
#pragma unroll
            for (int q = 0; q < 8; ++q)
                acc[q] += (f0[q] + f1[q]) + (f2[q] + f3[q]);
        }
        for (; k < e; ++k) {
            float4 r = *(const float4*)(hs + (size_t)adj[k] * 16 + hf * 8);
            float f[8];
            unpack8(r, f);
#pragma unroll
            for (int q = 0; q < 8; ++q) acc[q] += f[q];
        }
        if (!PASSB) {
            float* pp = partial + (size_t)v * 16 + hf * 8;
            *(float4*)pp = make_float4(acc[0], acc[1], acc[2], acc[3]);
            *(float4*)(pp + 4) = make_float4(acc[4], acc[5], acc[6], acc[7]);
        } else {
            float4 rs = *(const float4*)(hs + (size_t)v * 16 + hf * 8);
            float fs[8];
            unpack8(rs, fs);
            const float dv = dinv[v];
            if (L1) {
                __half2 hr[4];
#pragma unroll
                for (int q = 0; q < 4; ++q) {
                    float v0 = dv * fmaxf(dv * (acc[2 * q] + fs[2 * q]) +
                                              bias[hf * 8 + 2 * q],
                                          0.f);
                    float v1 = dv * fmaxf(dv * (acc[2 * q + 1] + fs[2 * q + 1]) +
                                              bias[hf * 8 + 2 * q + 1],
                                          0.f);
                    hr[q] = __floats2half2_rn(v0, v1);
                }
                *(float4*)((__half*)o + (size_t)v * 16 + hf * 8) =
                    *(const float4*)hr;
            } else {
                float prev[8];
#pragma unroll
                for (int q = 0; q < 8; ++q)
                    prev[q] = dv * (acc[q] + fs[q]);
                float po[32];
#pragma unroll
                for (int c = 0; c < 32; ++c) po[c] = 0.f;
#pragma unroll
                for (int j = 0; j < 8; ++j) {
                    const float* wrow = &W2s[(hf * 8 + j) * 32];
#pragma unroll
                    for (int c = 0; c < 32; ++c) po[c] += prev[j] * wrow[c];
                }
#pragma unroll
                for (int c = 0; c < 32; ++c)
                    po[c] += __shfl_xor(po[c], 1, 64);
                float* op = (float*)o + (size_t)v * 32 + hf * 16;
#pragma unroll
                for (int g = 0; g < 4; ++g) {
                    int c0 = hf * 16 + 4 * g;
                    *(float4*)(op + 4 * g) = make_float4(
                        po[c0] + bias[c0], po[c0 + 1] + bias[c0 + 1],
                        po[c0 + 2] + bias[c0 + 2], po[c0 + 3] + bias[c0 + 3]);
                }
            }
        }
    }
}

static inline int blocks_for(long long total) {
    return (int)((total + TPB - 1) / TPB);
}

extern "C" void kernel_launch(void* const* d_in, const int* in_sizes, int n_in,
                              void* d_out, int out_size, void* d_ws,
                              size_t ws_size, hipStream_t stream) {
    const float* x = (const float*)d_in[0];
    const int* ei = (const int*)d_in[1];
    const float* W1 = (const float*)d_in[2];
    const float* b1 = (const float*)d_in[3];
    const float* W2 = (const float*)d_in[4];
    const float* b2 = (const float*)d_in[5];
    float* out = (float*)d_out;

    const int n = in_sizes[0] / 128;  // 200000 nodes
    const int E = in_sizes[1] / 2;    // 6400000 edges
    const int* src = ei;
    const int* dst = ei + E;
    const int nbuck = (n + BUCKN - 1) / BUCKN;  // 196
    const int h = (n + 1) / 2;                  // src-half boundary

    char* ws = (char*)d_ws;
    float* dinv = (float*)ws;
    int* rp2 = (int*)(ws + (size_t)n * 4);
    int* adj = (int*)(ws + (size_t)n * 12);
    char* R = ws + (size_t)n * 12 + (size_t)E * 4;
    size_t base_bytes = (size_t)n * 12 + (size_t)E * 8;

    auto need = [&](int nbb) {
        return base_bytes +
               ((size_t)nbb + (size_t)nbb / SEGROWS + 2) * nbuck * 4 + 8192;
    };
    const int NBB =
        (ws_size >= need(2048)) ? 2048 : ((ws_size >= need(1024)) ? 1024 : 512);
    const int nseg = NBB / SEGROWS;
    const int chunk = (((E + NBB - 1) / NBB) + 3) & ~3;  // x4 for int4 loads

    int* hist = (int*)(R + (size_t)E * 4);
    int* segsum = hist + (size_t)NBB * nbuck;
    int* colsum = segsum + (size_t)nseg * nbuck;
    int* bstart = colsum + nbuck;
    int* bbuf = (int*)R;

    __half* h1s = (__half*)R;
    __half* z1s = (__half*)(R + (size_t)n * 32);
    float* partial = (float*)(R + (size_t)n * 64);

    const int cb = (nbuck + 255) / 256;  // 1

    // --- build ---
    k_hist<<<NBB, BINT, 0, stream>>>(dst, E, n, nbuck, chunk, hist);
    k_scanA1<<<dim3(cb, nseg), 256, 0, stream>>>(hist, nbuck, segsum);
    k_scanA2<<<cb, 256, 0, stream>>>(segsum, nbuck, nseg, colsum);
    k_scanB<<<1, 256, 0, stream>>>(colsum, nbuck, E, bstart);
    k_scanA3<<<dim3(cb, nseg), 256, 0, stream>>>(hist, nbuck, segsum);
    k_bin<<<NBB, BINT, 0, stream>>>(src, dst, E, n, nbuck, chunk, hist, bstart,
                                    bbuf);
    k_bucket2<<<nbuck, 1024, 0, stream>>>(bbuf, bstart, n, h, rp2, dinv, adj);

    // --- layer 1 ---
    k_mm1<<<(n + MMN - 1) / MMN, 512, 0, stream>>>(x, W1, dinv, n, h1s);
    k_gn<true, false><<<blocks_for(2LL * n), TPB, 0, stream>>>(
        rp2, bstart, adj, dinv, h1s, b1, nullptr, partial, nullptr, n);
    k_gn<true, true><<<blocks_for(2LL * n), TPB, 0, stream>>>(
        rp2, bstart, adj, dinv, h1s, b1, nullptr, partial, z1s, n);

    // --- layer 2 (k_out fused into gnB) ---
    k_gn<false, false><<<blocks_for(2LL * n), TPB, 0, stream>>>(
        rp2, bstart, adj, dinv, z1s, nullptr, nullptr, partial, nullptr, n);
    k_gn<false, true><<<blocks_for(2LL * n), TPB, 0, stream>>>(
        rp2, bstart, adj, dinv, z1s, b2, W2, partial, out, n);
}